// Round 1
// baseline (1383.136 us; speedup 1.0000x reference)
//
#include <hip/hip_runtime.h>

#define N_USERS 30000
#define N_ITEMS 60000
#define N_NODES 90000
#define NNZ     2000000
#define D       64
#define N_LAYERS 3
#define OUT_STRIDE ((N_LAYERS + 1) * D)   // 256

// ---------------------------------------------------------------------------
// init: ego = concat(user_emb, item_emb); out slot 0 = raw ego
// ---------------------------------------------------------------------------
__global__ void init_ego_kernel(const float* __restrict__ user_emb,
                                const float* __restrict__ item_emb,
                                float* __restrict__ ego,
                                float* __restrict__ out) {
    int idx = blockIdx.x * blockDim.x + threadIdx.x;   // over N_NODES*D/4 float4s
    const int total = N_NODES * (D / 4);
    if (idx >= total) return;
    int n  = idx / (D / 4);
    int c4 = idx % (D / 4);
    float4 v;
    if (n < N_USERS)
        v = ((const float4*)user_emb)[n * (D / 4) + c4];
    else
        v = ((const float4*)item_emb)[(n - N_USERS) * (D / 4) + c4];
    ((float4*)ego)[idx] = v;
    ((float4*)out)[n * (OUT_STRIDE / 4) + c4] = v;     // slot 0, raw ego
}

// ---------------------------------------------------------------------------
// CSR build: histogram -> scan -> fill
// ---------------------------------------------------------------------------
__global__ void hist_kernel(const int* __restrict__ adj_row,
                            int* __restrict__ counts) {
    int i = blockIdx.x * blockDim.x + threadIdx.x;
    int stride = gridDim.x * blockDim.x;
    for (; i < NNZ; i += stride)
        atomicAdd(&counts[adj_row[i]], 1);
}

__global__ void scan_kernel(const int* __restrict__ counts,
                            int* __restrict__ row_ptr) {
    __shared__ int sums[1024];
    const int n = N_NODES;
    const int chunk = (n + 1023) / 1024;               // 88
    int tid = threadIdx.x;
    int beg = tid * chunk;
    int end = min(beg + chunk, n);
    int s = 0;
    for (int i = beg; i < end; i++) s += counts[i];
    sums[tid] = s;
    __syncthreads();
    // Hillis-Steele inclusive scan over the 1024 partial sums
    for (int off = 1; off < 1024; off <<= 1) {
        int v = (tid >= off) ? sums[tid - off] : 0;
        __syncthreads();
        sums[tid] += v;
        __syncthreads();
    }
    int excl = (tid == 0) ? 0 : sums[tid - 1];
    for (int i = beg; i < end; i++) { row_ptr[i] = excl; excl += counts[i]; }
    if (tid == 1023) row_ptr[n] = sums[1023];          // == NNZ
}

__global__ void fill_kernel(const int* __restrict__ adj_row,
                            const int* __restrict__ adj_col,
                            const float* __restrict__ adj_val,
                            const int* __restrict__ row_ptr,
                            int* __restrict__ fillc,
                            int* __restrict__ pcol,
                            float* __restrict__ pval) {
    int i = blockIdx.x * blockDim.x + threadIdx.x;
    int stride = gridDim.x * blockDim.x;
    for (; i < NNZ; i += stride) {
        int r = adj_row[i];
        int pos = row_ptr[r] + atomicAdd(&fillc[r], 1);
        pcol[pos] = adj_col[i];
        pval[pos] = adj_val[i];
    }
}

// ---------------------------------------------------------------------------
// SpMM: side[r][d] = sum over edges of row r: ego[col][d] * val
// one wave per row, lane = feature d -> coalesced 256B gathers
// ---------------------------------------------------------------------------
__global__ __launch_bounds__(256) void spmm_kernel(const int* __restrict__ row_ptr,
                                                   const int* __restrict__ pcol,
                                                   const float* __restrict__ pval,
                                                   const float* __restrict__ ego,
                                                   float* __restrict__ side) {
    int wave = (blockIdx.x * blockDim.x + threadIdx.x) >> 6;
    int lane = threadIdx.x & 63;
    if (wave >= N_NODES) return;
    int beg = row_ptr[wave];
    int end = row_ptr[wave + 1];
    float acc = 0.f;
    for (int i = beg; i < end; i++) {
        int   c = pcol[i];     // wave-uniform load (broadcast)
        float v = pval[i];
        acc = fmaf(ego[c * D + lane], v, acc);
    }
    side[wave * D + lane] = acc;
}

// ---------------------------------------------------------------------------
// dense: sum_e = lrelu(side@Wgc+bgc); bi_e = lrelu((ego*side)@Wbi+bbi)
//        ego = sum_e + bi_e ; out slot = l2norm(ego)
// one wave per row; W staged in LDS
// ---------------------------------------------------------------------------
__global__ __launch_bounds__(256) void dense_kernel(const float* __restrict__ side,
                                                    float* __restrict__ ego,
                                                    const float* __restrict__ Wgc,
                                                    const float* __restrict__ bgc,
                                                    const float* __restrict__ Wbi,
                                                    const float* __restrict__ bbi,
                                                    float* __restrict__ out,
                                                    int slot) {
    __shared__ float sWgc[D * D];
    __shared__ float sWbi[D * D];
    __shared__ float sbgc[D];
    __shared__ float sbbi[D];
    for (int i = threadIdx.x; i < D * D; i += blockDim.x) {
        sWgc[i] = Wgc[i];
        sWbi[i] = Wbi[i];
    }
    if (threadIdx.x < D) {
        sbgc[threadIdx.x] = bgc[threadIdx.x];
        sbbi[threadIdx.x] = bbi[threadIdx.x];
    }
    __syncthreads();

    int lane = threadIdx.x & 63;
    int waveInBlock = threadIdx.x >> 6;
    int wavesPerBlock = blockDim.x >> 6;
    int waveGlobal = blockIdx.x * wavesPerBlock + waveInBlock;
    int nWaves = gridDim.x * wavesPerBlock;

    for (int r = waveGlobal; r < N_NODES; r += nWaves) {
        float s = side[r * D + lane];
        float e = ego[r * D + lane];
        float p = e * s;
        float acc1 = sbgc[lane];
        float acc2 = sbbi[lane];
#pragma unroll
        for (int j = 0; j < D; j++) {
            float sj = __shfl(s, j);
            float pj = __shfl(p, j);
            acc1 = fmaf(sj, sWgc[j * D + lane], acc1);
            acc2 = fmaf(pj, sWbi[j * D + lane], acc2);
        }
        acc1 = acc1 > 0.f ? acc1 : 0.2f * acc1;
        acc2 = acc2 > 0.f ? acc2 : 0.2f * acc2;
        float en = acc1 + acc2;

        // l2 norm across the 64-lane row
        float ss = en * en;
#pragma unroll
        for (int off = 32; off > 0; off >>= 1)
            ss += __shfl_xor(ss, off);
        float nrm = fmaxf(sqrtf(ss), 1e-12f);

        ego[r * D + lane] = en;
        out[r * OUT_STRIDE + slot * D + lane] = en / nrm;
    }
}

// ---------------------------------------------------------------------------
extern "C" void kernel_launch(void* const* d_in, const int* in_sizes, int n_in,
                              void* d_out, int out_size, void* d_ws, size_t ws_size,
                              hipStream_t stream) {
    const float* user_emb = (const float*)d_in[0];
    const float* item_emb = (const float*)d_in[1];
    const int*   adj_row  = (const int*)d_in[2];
    const int*   adj_col  = (const int*)d_in[3];
    const float* adj_val  = (const float*)d_in[4];
    const float* W_gc     = (const float*)d_in[5];
    const float* b_gc     = (const float*)d_in[6];
    const float* W_bi     = (const float*)d_in[7];
    const float* b_bi     = (const float*)d_in[8];
    float* out = (float*)d_out;

    char* ws = (char*)d_ws;
    size_t off = 0;
    auto alloc = [&](size_t bytes) -> void* {
        void* p = ws + off;
        off += (bytes + 255) / 256 * 256;
        return p;
    };
    float* ego     = (float*)alloc((size_t)N_NODES * D * 4);
    float* side    = (float*)alloc((size_t)N_NODES * D * 4);
    int*   row_ptr = (int*)alloc((size_t)(N_NODES + 1) * 4);
    int*   counts  = (int*)alloc((size_t)N_NODES * 4);
    int*   fillc   = (int*)alloc((size_t)N_NODES * 4);
    int*   pcol    = (int*)alloc((size_t)NNZ * 4);
    float* pval    = (float*)alloc((size_t)NNZ * 4);

    hipMemsetAsync(counts, 0, (size_t)N_NODES * 4, stream);
    hipMemsetAsync(fillc,  0, (size_t)N_NODES * 4, stream);

    hist_kernel<<<2048, 256, 0, stream>>>(adj_row, counts);
    scan_kernel<<<1, 1024, 0, stream>>>(counts, row_ptr);
    fill_kernel<<<2048, 256, 0, stream>>>(adj_row, adj_col, adj_val,
                                          row_ptr, fillc, pcol, pval);

    init_ego_kernel<<<(N_NODES * (D / 4) + 255) / 256, 256, 0, stream>>>(
        user_emb, item_emb, ego, out);

    for (int k = 0; k < N_LAYERS; k++) {
        spmm_kernel<<<(N_NODES + 3) / 4, 256, 0, stream>>>(
            row_ptr, pcol, pval, ego, side);
        dense_kernel<<<1024, 256, 0, stream>>>(
            side, ego,
            W_gc + (size_t)k * D * D, b_gc + (size_t)k * D,
            W_bi + (size_t)k * D * D, b_bi + (size_t)k * D,
            out, k + 1);
    }
}

// Round 2
// 1140.811 us; speedup vs baseline: 1.2124x; 1.2124x over previous
//
#include <hip/hip_runtime.h>

#define N_USERS 30000
#define N_ITEMS 60000
#define N_NODES 90000
#define NNZ     2000000
#define D       64
#define N_LAYERS 3
#define OUT_STRIDE ((N_LAYERS + 1) * D)   // 256

// ---------------------------------------------------------------------------
// init: ego = concat(user_emb, item_emb); out slot 0 = raw ego
// ---------------------------------------------------------------------------
__global__ void init_ego_kernel(const float* __restrict__ user_emb,
                                const float* __restrict__ item_emb,
                                float* __restrict__ ego,
                                float* __restrict__ out) {
    int idx = blockIdx.x * blockDim.x + threadIdx.x;   // over N_NODES*D/4 float4s
    const int total = N_NODES * (D / 4);
    if (idx >= total) return;
    int n  = idx / (D / 4);
    int c4 = idx % (D / 4);
    float4 v;
    if (n < N_USERS)
        v = ((const float4*)user_emb)[n * (D / 4) + c4];
    else
        v = ((const float4*)item_emb)[(n - N_USERS) * (D / 4) + c4];
    ((float4*)ego)[idx] = v;
    ((float4*)out)[n * (OUT_STRIDE / 4) + c4] = v;     // slot 0, raw ego
}

// ---------------------------------------------------------------------------
// CSR build: histogram -> scan -> fill (packed int2 {col, bitcast(val)})
// ---------------------------------------------------------------------------
__global__ void hist_kernel(const int* __restrict__ adj_row,
                            int* __restrict__ counts) {
    int i = blockIdx.x * blockDim.x + threadIdx.x;
    int stride = gridDim.x * blockDim.x;
    for (; i < NNZ; i += stride)
        atomicAdd(&counts[adj_row[i]], 1);
}

// single-block scan; also seeds fillpos = row_ptr copy
__global__ void scan_kernel(const int* __restrict__ counts,
                            int* __restrict__ row_ptr,
                            int* __restrict__ fillpos) {
    __shared__ int sums[1024];
    const int n = N_NODES;
    const int chunk = (n + 1023) / 1024;               // 88
    int tid = threadIdx.x;
    int beg = tid * chunk;
    int end = min(beg + chunk, n);
    int s = 0;
    int i = beg;
    for (; i + 4 <= end; i += 4) {
        int4 c = *(const int4*)&counts[i];
        s += c.x + c.y + c.z + c.w;
    }
    for (; i < end; i++) s += counts[i];
    sums[tid] = s;
    __syncthreads();
    for (int off = 1; off < 1024; off <<= 1) {
        int v = (tid >= off) ? sums[tid - off] : 0;
        __syncthreads();
        sums[tid] += v;
        __syncthreads();
    }
    int excl = (tid == 0) ? 0 : sums[tid - 1];
    for (i = beg; i < end; i++) {
        row_ptr[i] = excl;
        fillpos[i] = excl;
        excl += counts[i];
    }
    if (tid == 1023) row_ptr[n] = sums[1023];          // == NNZ
}

__global__ void fill_kernel(const int* __restrict__ adj_row,
                            const int* __restrict__ adj_col,
                            const float* __restrict__ adj_val,
                            int* __restrict__ fillpos,
                            int2* __restrict__ pedge) {
    int i = blockIdx.x * blockDim.x + threadIdx.x;
    int stride = gridDim.x * blockDim.x;
    for (; i < NNZ; i += stride) {
        int r = adj_row[i];
        int pos = atomicAdd(&fillpos[r], 1);
        pedge[pos] = make_int2(adj_col[i], __float_as_int(adj_val[i]));
    }
}

// ---------------------------------------------------------------------------
// fused layer: side = A@ego_in (CSR gather), then
//   sum_e = lrelu(side@Wgc+bgc); bi_e = lrelu((ego_in*side)@Wbi+bbi)
//   ego_out = sum_e + bi_e ; out slot = l2norm(ego_out)
// one wave per row; lane = feature d
// ---------------------------------------------------------------------------
__global__ __launch_bounds__(512) void layer_kernel(
        const int* __restrict__ row_ptr,
        const int2* __restrict__ pedge,
        const float* __restrict__ ego_in,
        const float* __restrict__ Wgc,
        const float* __restrict__ bgc,
        const float* __restrict__ Wbi,
        const float* __restrict__ bbi,
        float* __restrict__ ego_out,
        float* __restrict__ out,
        int slot) {
    __shared__ float sWgc[D * D];
    __shared__ float sWbi[D * D];
    __shared__ float sbgc[D];
    __shared__ float sbbi[D];
    for (int i = threadIdx.x; i < D * D; i += blockDim.x) {
        sWgc[i] = Wgc[i];
        sWbi[i] = Wbi[i];
    }
    if (threadIdx.x < D) {
        sbgc[threadIdx.x] = bgc[threadIdx.x];
        sbbi[threadIdx.x] = bbi[threadIdx.x];
    }
    __syncthreads();

    int lane = threadIdx.x & 63;
    int waveInBlock = threadIdx.x >> 6;
    int wavesPerBlock = blockDim.x >> 6;
    int waveGlobal = blockIdx.x * wavesPerBlock + waveInBlock;
    int nWaves = gridDim.x * wavesPerBlock;

    for (int r = waveGlobal; r < N_NODES; r += nWaves) {
        int beg = row_ptr[r];
        int end = row_ptr[r + 1];
        float acc = 0.f;

        for (int base = beg; base < end; base += 64) {
            int cnt = min(64, end - base);
            int2 e = make_int2(0, 0);
            if (base + lane < end) e = pedge[base + lane];
            int   cl = e.x;
            int   vl = e.y;
            int j = 0;
            for (; j + 4 <= cnt; j += 4) {
                int c0 = __builtin_amdgcn_readlane(cl, j);
                int c1 = __builtin_amdgcn_readlane(cl, j + 1);
                int c2 = __builtin_amdgcn_readlane(cl, j + 2);
                int c3 = __builtin_amdgcn_readlane(cl, j + 3);
                float e0 = ego_in[(size_t)c0 * D + lane];
                float e1 = ego_in[(size_t)c1 * D + lane];
                float e2 = ego_in[(size_t)c2 * D + lane];
                float e3 = ego_in[(size_t)c3 * D + lane];
                float v0 = __int_as_float(__builtin_amdgcn_readlane(vl, j));
                float v1 = __int_as_float(__builtin_amdgcn_readlane(vl, j + 1));
                float v2 = __int_as_float(__builtin_amdgcn_readlane(vl, j + 2));
                float v3 = __int_as_float(__builtin_amdgcn_readlane(vl, j + 3));
                acc = fmaf(e0, v0, acc);
                acc = fmaf(e1, v1, acc);
                acc = fmaf(e2, v2, acc);
                acc = fmaf(e3, v3, acc);
            }
            for (; j < cnt; j++) {
                int   c = __builtin_amdgcn_readlane(cl, j);
                float v = __int_as_float(__builtin_amdgcn_readlane(vl, j));
                acc = fmaf(ego_in[(size_t)c * D + lane], v, acc);
            }
        }

        // dense part
        float s = acc;
        float ein = ego_in[(size_t)r * D + lane];
        float p = ein * s;
        float acc1 = sbgc[lane];
        float acc2 = sbbi[lane];
#pragma unroll
        for (int j = 0; j < D; j++) {
            float sj = __shfl(s, j);
            float pj = __shfl(p, j);
            acc1 = fmaf(sj, sWgc[j * D + lane], acc1);
            acc2 = fmaf(pj, sWbi[j * D + lane], acc2);
        }
        acc1 = acc1 > 0.f ? acc1 : 0.2f * acc1;
        acc2 = acc2 > 0.f ? acc2 : 0.2f * acc2;
        float en = acc1 + acc2;

        float ss = en * en;
#pragma unroll
        for (int off = 32; off > 0; off >>= 1)
            ss += __shfl_xor(ss, off);
        float nrm = fmaxf(sqrtf(ss), 1e-12f);

        ego_out[(size_t)r * D + lane] = en;
        out[(size_t)r * OUT_STRIDE + slot * D + lane] = en / nrm;
    }
}

// ---------------------------------------------------------------------------
extern "C" void kernel_launch(void* const* d_in, const int* in_sizes, int n_in,
                              void* d_out, int out_size, void* d_ws, size_t ws_size,
                              hipStream_t stream) {
    const float* user_emb = (const float*)d_in[0];
    const float* item_emb = (const float*)d_in[1];
    const int*   adj_row  = (const int*)d_in[2];
    const int*   adj_col  = (const int*)d_in[3];
    const float* adj_val  = (const float*)d_in[4];
    const float* W_gc     = (const float*)d_in[5];
    const float* b_gc     = (const float*)d_in[6];
    const float* W_bi     = (const float*)d_in[7];
    const float* b_bi     = (const float*)d_in[8];
    float* out = (float*)d_out;

    char* ws = (char*)d_ws;
    size_t off = 0;
    auto alloc = [&](size_t bytes) -> void* {
        void* p = ws + off;
        off += (bytes + 255) / 256 * 256;
        return p;
    };
    float* ego0    = (float*)alloc((size_t)N_NODES * D * 4);
    float* ego1    = (float*)alloc((size_t)N_NODES * D * 4);
    int*   row_ptr = (int*)alloc((size_t)(N_NODES + 1) * 4);
    int*   counts  = (int*)alloc((size_t)N_NODES * 4);
    int*   fillpos = (int*)alloc((size_t)N_NODES * 4);
    int2*  pedge   = (int2*)alloc((size_t)NNZ * 8);

    hipMemsetAsync(counts, 0, (size_t)N_NODES * 4, stream);

    hist_kernel<<<2048, 256, 0, stream>>>(adj_row, counts);
    scan_kernel<<<1, 1024, 0, stream>>>(counts, row_ptr, fillpos);
    fill_kernel<<<2048, 256, 0, stream>>>(adj_row, adj_col, adj_val,
                                          fillpos, pedge);

    init_ego_kernel<<<(N_NODES * (D / 4) + 255) / 256, 256, 0, stream>>>(
        user_emb, item_emb, ego0, out);

    float* bufs[2] = {ego0, ego1};
    for (int k = 0; k < N_LAYERS; k++) {
        layer_kernel<<<1024, 512, 0, stream>>>(
            row_ptr, pedge, bufs[k & 1],
            W_gc + (size_t)k * D * D, b_gc + (size_t)k * D,
            W_bi + (size_t)k * D * D, b_bi + (size_t)k * D,
            bufs[(k + 1) & 1], out, k + 1);
    }
}

// Round 3
// 905.918 us; speedup vs baseline: 1.5268x; 1.2593x over previous
//
#include <hip/hip_runtime.h>

#define N_USERS 30000
#define N_ITEMS 60000
#define N_NODES 90000
#define NNZ     2000000
#define D       64
#define N_LAYERS 3
#define OUT_STRIDE ((N_LAYERS + 1) * D)   // 256

// ---------------------------------------------------------------------------
// init: ego = concat(user_emb, item_emb); out slot 0 = raw ego
// ---------------------------------------------------------------------------
__global__ void init_ego_kernel(const float* __restrict__ user_emb,
                                const float* __restrict__ item_emb,
                                float* __restrict__ ego,
                                float* __restrict__ out) {
    int idx = blockIdx.x * blockDim.x + threadIdx.x;   // over N_NODES*D/4 float4s
    const int total = N_NODES * (D / 4);
    if (idx >= total) return;
    int n  = idx / (D / 4);
    int c4 = idx % (D / 4);
    float4 v;
    if (n < N_USERS)
        v = ((const float4*)user_emb)[n * (D / 4) + c4];
    else
        v = ((const float4*)item_emb)[(n - N_USERS) * (D / 4) + c4];
    ((float4*)ego)[idx] = v;
    ((float4*)out)[n * (OUT_STRIDE / 4) + c4] = v;     // slot 0, raw ego
}

// ---------------------------------------------------------------------------
// CSR build: histogram -> scan -> fill (packed int2 {col, bitcast(val)})
// ---------------------------------------------------------------------------
__global__ void hist_kernel(const int* __restrict__ adj_row,
                            int* __restrict__ counts) {
    int i = blockIdx.x * blockDim.x + threadIdx.x;
    int stride = gridDim.x * blockDim.x;
    for (; i < NNZ; i += stride)
        atomicAdd(&counts[adj_row[i]], 1);
}

// single-block scan; also seeds fillpos = row_ptr copy
__global__ void scan_kernel(const int* __restrict__ counts,
                            int* __restrict__ row_ptr,
                            int* __restrict__ fillpos) {
    __shared__ int sums[1024];
    const int n = N_NODES;
    const int chunk = (n + 1023) / 1024;               // 88
    int tid = threadIdx.x;
    int beg = tid * chunk;
    int end = min(beg + chunk, n);
    int s = 0;
    int i = beg;
    for (; i + 4 <= end; i += 4) {
        int4 c = *(const int4*)&counts[i];
        s += c.x + c.y + c.z + c.w;
    }
    for (; i < end; i++) s += counts[i];
    sums[tid] = s;
    __syncthreads();
    for (int off = 1; off < 1024; off <<= 1) {
        int v = (tid >= off) ? sums[tid - off] : 0;
        __syncthreads();
        sums[tid] += v;
        __syncthreads();
    }
    int excl = (tid == 0) ? 0 : sums[tid - 1];
    for (i = beg; i < end; i++) {
        row_ptr[i] = excl;
        fillpos[i] = excl;
        excl += counts[i];
    }
    if (tid == 1023) row_ptr[n] = sums[1023];          // == NNZ
}

__global__ void fill_kernel(const int* __restrict__ adj_row,
                            const int* __restrict__ adj_col,
                            const float* __restrict__ adj_val,
                            int* __restrict__ fillpos,
                            int2* __restrict__ pedge) {
    int i = blockIdx.x * blockDim.x + threadIdx.x;
    int stride = gridDim.x * blockDim.x;
    for (; i < NNZ; i += stride) {
        int r = adj_row[i];
        int pos = atomicAdd(&fillpos[r], 1);
        pedge[pos] = make_int2(adj_col[i], __float_as_int(adj_val[i]));
    }
}

// ---------------------------------------------------------------------------
// SpMM: side[r][d] = sum over edges of row r: ego[col][d] * val
// one wave per row, lane = feature d. Coalesced int2 edge loads, readlane
// broadcast (SGPR col -> saddr gathers), 8 gathers in flight.
// ---------------------------------------------------------------------------
__global__ __launch_bounds__(256) void spmm_kernel(const int* __restrict__ row_ptr,
                                                   const int2* __restrict__ pedge,
                                                   const float* __restrict__ ego,
                                                   float* __restrict__ side) {
    int wave = (blockIdx.x * blockDim.x + threadIdx.x) >> 6;
    int lane = threadIdx.x & 63;
    if (wave >= N_NODES) return;
    int beg = row_ptr[wave];
    int end = row_ptr[wave + 1];
    float acc = 0.f;

    for (int base = beg; base < end; base += 64) {
        int cnt = min(64, end - base);
        int2 e = make_int2(0, 0);
        if (base + lane < end) e = pedge[base + lane];
        int cl = e.x;
        int vl = e.y;
        int j = 0;
        for (; j + 8 <= cnt; j += 8) {
            int c0 = __builtin_amdgcn_readlane(cl, j + 0);
            int c1 = __builtin_amdgcn_readlane(cl, j + 1);
            int c2 = __builtin_amdgcn_readlane(cl, j + 2);
            int c3 = __builtin_amdgcn_readlane(cl, j + 3);
            int c4 = __builtin_amdgcn_readlane(cl, j + 4);
            int c5 = __builtin_amdgcn_readlane(cl, j + 5);
            int c6 = __builtin_amdgcn_readlane(cl, j + 6);
            int c7 = __builtin_amdgcn_readlane(cl, j + 7);
            float g0 = ego[(c0 << 6) + lane];
            float g1 = ego[(c1 << 6) + lane];
            float g2 = ego[(c2 << 6) + lane];
            float g3 = ego[(c3 << 6) + lane];
            float g4 = ego[(c4 << 6) + lane];
            float g5 = ego[(c5 << 6) + lane];
            float g6 = ego[(c6 << 6) + lane];
            float g7 = ego[(c7 << 6) + lane];
            float v0 = __int_as_float(__builtin_amdgcn_readlane(vl, j + 0));
            float v1 = __int_as_float(__builtin_amdgcn_readlane(vl, j + 1));
            float v2 = __int_as_float(__builtin_amdgcn_readlane(vl, j + 2));
            float v3 = __int_as_float(__builtin_amdgcn_readlane(vl, j + 3));
            float v4 = __int_as_float(__builtin_amdgcn_readlane(vl, j + 4));
            float v5 = __int_as_float(__builtin_amdgcn_readlane(vl, j + 5));
            float v6 = __int_as_float(__builtin_amdgcn_readlane(vl, j + 6));
            float v7 = __int_as_float(__builtin_amdgcn_readlane(vl, j + 7));
            acc = fmaf(g0, v0, acc);
            acc = fmaf(g1, v1, acc);
            acc = fmaf(g2, v2, acc);
            acc = fmaf(g3, v3, acc);
            acc = fmaf(g4, v4, acc);
            acc = fmaf(g5, v5, acc);
            acc = fmaf(g6, v6, acc);
            acc = fmaf(g7, v7, acc);
        }
        for (; j < cnt; j++) {
            int   c = __builtin_amdgcn_readlane(cl, j);
            float v = __int_as_float(__builtin_amdgcn_readlane(vl, j));
            acc = fmaf(ego[(c << 6) + lane], v, acc);
        }
    }
    side[(size_t)wave * D + lane] = acc;
}

// ---------------------------------------------------------------------------
// dense: sum_e = lrelu(side@Wgc+bgc); bi_e = lrelu((ego*side)@Wbi+bbi)
//        ego_out = sum_e + bi_e ; out slot = l2norm(ego_out)
// 2 rows per wave; W staged in LDS; s/p rows staged in LDS, read as
// uniform float4 broadcasts; each W-column ds_read shared by both rows.
// ---------------------------------------------------------------------------
__global__ __launch_bounds__(256) void dense_kernel(const float* __restrict__ side,
                                                    const float* __restrict__ ego_in,
                                                    const float* __restrict__ Wgc,
                                                    const float* __restrict__ bgc,
                                                    const float* __restrict__ Wbi,
                                                    const float* __restrict__ bbi,
                                                    float* __restrict__ ego_out,
                                                    float* __restrict__ out,
                                                    int slot) {
    __shared__ float sWgc[D * D];
    __shared__ float sWbi[D * D];
    __shared__ float sbgc[D];
    __shared__ float sbbi[D];
    __shared__ float sRow[4][4][D];   // [waveInBlock][{s0,p0,s1,p1}][lane]

    for (int i = threadIdx.x; i < D * D; i += blockDim.x) {
        sWgc[i] = Wgc[i];
        sWbi[i] = Wbi[i];
    }
    if (threadIdx.x < D) {
        sbgc[threadIdx.x] = bgc[threadIdx.x];
        sbbi[threadIdx.x] = bbi[threadIdx.x];
    }
    __syncthreads();

    int lane = threadIdx.x & 63;
    int wib  = threadIdx.x >> 6;
    int wave = blockIdx.x * 4 + wib;
    int r0 = wave * 2;
    int r1 = r0 + 1;                  // N_NODES even; grid sized exactly

    float s0 = side[(size_t)r0 * D + lane];
    float e0 = ego_in[(size_t)r0 * D + lane];
    float s1 = side[(size_t)r1 * D + lane];
    float e1 = ego_in[(size_t)r1 * D + lane];
    float p0 = e0 * s0;
    float p1 = e1 * s1;

    sRow[wib][0][lane] = s0;
    sRow[wib][1][lane] = p0;
    sRow[wib][2][lane] = s1;
    sRow[wib][3][lane] = p1;
    // same-wave LDS RAW: compiler inserts lgkmcnt waits

    float a10 = sbgc[lane];   // row0 gc
    float a20 = sbbi[lane];   // row0 bi
    float a11 = sbgc[lane];   // row1 gc
    float a21 = sbbi[lane];   // row1 bi

#pragma unroll
    for (int j4 = 0; j4 < D; j4 += 4) {
        float4 sv0 = *(const float4*)&sRow[wib][0][j4];
        float4 pv0 = *(const float4*)&sRow[wib][1][j4];
        float4 sv1 = *(const float4*)&sRow[wib][2][j4];
        float4 pv1 = *(const float4*)&sRow[wib][3][j4];
        const float* sA = (const float*)&sv0;
        const float* pA = (const float*)&pv0;
        const float* sB = (const float*)&sv1;
        const float* pB = (const float*)&pv1;
#pragma unroll
        for (int jj = 0; jj < 4; jj++) {
            float wg = sWgc[(j4 + jj) * D + lane];
            float wb = sWbi[(j4 + jj) * D + lane];
            a10 = fmaf(sA[jj], wg, a10);
            a20 = fmaf(pA[jj], wb, a20);
            a11 = fmaf(sB[jj], wg, a11);
            a21 = fmaf(pB[jj], wb, a21);
        }
    }

    a10 = a10 > 0.f ? a10 : 0.2f * a10;
    a20 = a20 > 0.f ? a20 : 0.2f * a20;
    a11 = a11 > 0.f ? a11 : 0.2f * a11;
    a21 = a21 > 0.f ? a21 : 0.2f * a21;
    float en0 = a10 + a20;
    float en1 = a11 + a21;

    float ss0 = en0 * en0;
    float ss1 = en1 * en1;
#pragma unroll
    for (int off = 32; off > 0; off >>= 1) {
        ss0 += __shfl_xor(ss0, off);
        ss1 += __shfl_xor(ss1, off);
    }
    float nrm0 = fmaxf(sqrtf(ss0), 1e-12f);
    float nrm1 = fmaxf(sqrtf(ss1), 1e-12f);

    ego_out[(size_t)r0 * D + lane] = en0;
    ego_out[(size_t)r1 * D + lane] = en1;
    out[(size_t)r0 * OUT_STRIDE + slot * D + lane] = en0 / nrm0;
    out[(size_t)r1 * OUT_STRIDE + slot * D + lane] = en1 / nrm1;
}

// ---------------------------------------------------------------------------
extern "C" void kernel_launch(void* const* d_in, const int* in_sizes, int n_in,
                              void* d_out, int out_size, void* d_ws, size_t ws_size,
                              hipStream_t stream) {
    const float* user_emb = (const float*)d_in[0];
    const float* item_emb = (const float*)d_in[1];
    const int*   adj_row  = (const int*)d_in[2];
    const int*   adj_col  = (const int*)d_in[3];
    const float* adj_val  = (const float*)d_in[4];
    const float* W_gc     = (const float*)d_in[5];
    const float* b_gc     = (const float*)d_in[6];
    const float* W_bi     = (const float*)d_in[7];
    const float* b_bi     = (const float*)d_in[8];
    float* out = (float*)d_out;

    char* ws = (char*)d_ws;
    size_t off = 0;
    auto alloc = [&](size_t bytes) -> void* {
        void* p = ws + off;
        off += (bytes + 255) / 256 * 256;
        return p;
    };
    float* ego0    = (float*)alloc((size_t)N_NODES * D * 4);
    float* ego1    = (float*)alloc((size_t)N_NODES * D * 4);
    float* side    = (float*)alloc((size_t)N_NODES * D * 4);
    int*   row_ptr = (int*)alloc((size_t)(N_NODES + 1) * 4);
    int*   counts  = (int*)alloc((size_t)N_NODES * 4);
    int*   fillpos = (int*)alloc((size_t)N_NODES * 4);
    int2*  pedge   = (int2*)alloc((size_t)NNZ * 8);

    hipMemsetAsync(counts, 0, (size_t)N_NODES * 4, stream);

    hist_kernel<<<2048, 256, 0, stream>>>(adj_row, counts);
    scan_kernel<<<1, 1024, 0, stream>>>(counts, row_ptr, fillpos);
    fill_kernel<<<2048, 256, 0, stream>>>(adj_row, adj_col, adj_val,
                                          fillpos, pedge);

    init_ego_kernel<<<(N_NODES * (D / 4) + 255) / 256, 256, 0, stream>>>(
        user_emb, item_emb, ego0, out);

    float* bufs[2] = {ego0, ego1};
    for (int k = 0; k < N_LAYERS; k++) {
        spmm_kernel<<<(N_NODES + 3) / 4, 256, 0, stream>>>(
            row_ptr, pedge, bufs[k & 1], side);
        dense_kernel<<<N_NODES / 8, 256, 0, stream>>>(
            side, bufs[k & 1],
            W_gc + (size_t)k * D * D, b_gc + (size_t)k * D,
            W_bi + (size_t)k * D * D, b_bi + (size_t)k * D,
            bufs[(k + 1) & 1], out, k + 1);
    }
}

// Round 4
// 723.181 us; speedup vs baseline: 1.9126x; 1.2527x over previous
//
#include <hip/hip_runtime.h>

#define N_USERS 30000
#define N_ITEMS 60000
#define N_NODES 90000
#define NNZ     2000000
#define D       64
#define N_LAYERS 3
#define OUT_STRIDE ((N_LAYERS + 1) * D)   // 256

#define SCAN_BLOCK 1024
#define N_SCAN_BLOCKS ((N_NODES + SCAN_BLOCK - 1) / SCAN_BLOCK)   // 88

// ---------------------------------------------------------------------------
// init: ego = concat(user_emb, item_emb); out slot 0 = raw ego
// ---------------------------------------------------------------------------
__global__ void init_ego_kernel(const float* __restrict__ user_emb,
                                const float* __restrict__ item_emb,
                                float* __restrict__ ego,
                                float* __restrict__ out) {
    int idx = blockIdx.x * blockDim.x + threadIdx.x;   // over N_NODES*D/4 float4s
    const int total = N_NODES * (D / 4);
    if (idx >= total) return;
    int n  = idx / (D / 4);
    int c4 = idx % (D / 4);
    float4 v;
    if (n < N_USERS)
        v = ((const float4*)user_emb)[n * (D / 4) + c4];
    else
        v = ((const float4*)item_emb)[(n - N_USERS) * (D / 4) + c4];
    ((float4*)ego)[idx] = v;
    ((float4*)out)[n * (OUT_STRIDE / 4) + c4] = v;     // slot 0, raw ego
}

// ---------------------------------------------------------------------------
// CSR build: histogram -> 3-phase scan -> fill (packed int2 {col, val})
// ---------------------------------------------------------------------------
__global__ void hist_kernel(const int* __restrict__ adj_row,
                            int* __restrict__ counts) {
    int i = blockIdx.x * blockDim.x + threadIdx.x;
    int stride = gridDim.x * blockDim.x;
    for (; i < NNZ; i += stride)
        atomicAdd(&counts[adj_row[i]], 1);
}

// phase 1: per-block sums (coalesced + LDS tree reduce)
__global__ __launch_bounds__(SCAN_BLOCK) void scan_phase1(
        const int* __restrict__ counts, int* __restrict__ blockSums) {
    __shared__ int red[SCAN_BLOCK];
    int i = blockIdx.x * SCAN_BLOCK + threadIdx.x;
    int v = (i < N_NODES) ? counts[i] : 0;
    red[threadIdx.x] = v;
    __syncthreads();
    for (int off = SCAN_BLOCK / 2; off > 0; off >>= 1) {
        if (threadIdx.x < off) red[threadIdx.x] += red[threadIdx.x + off];
        __syncthreads();
    }
    if (threadIdx.x == 0) blockSums[blockIdx.x] = red[0];
}

// phase 2: exclusive scan of the 88 block sums (single small block)
__global__ __launch_bounds__(128) void scan_phase2(int* __restrict__ blockSums) {
    __shared__ int s[128];
    int t = threadIdx.x;
    int v = (t < N_SCAN_BLOCKS) ? blockSums[t] : 0;
    s[t] = v;
    __syncthreads();
    for (int off = 1; off < 128; off <<= 1) {
        int x = (t >= off) ? s[t - off] : 0;
        __syncthreads();
        s[t] += x;
        __syncthreads();
    }
    if (t < N_SCAN_BLOCKS) blockSums[t] = s[t] - v;    // exclusive
}

// phase 3: local inclusive scan + block offset -> row_ptr, fillpos
__global__ __launch_bounds__(SCAN_BLOCK) void scan_phase3(
        const int* __restrict__ counts, const int* __restrict__ blockSums,
        int* __restrict__ row_ptr, int* __restrict__ fillpos) {
    __shared__ int s[SCAN_BLOCK];
    int t = threadIdx.x;
    int i = blockIdx.x * SCAN_BLOCK + t;
    int v = (i < N_NODES) ? counts[i] : 0;
    s[t] = v;
    __syncthreads();
    for (int off = 1; off < SCAN_BLOCK; off <<= 1) {
        int x = (t >= off) ? s[t - off] : 0;
        __syncthreads();
        s[t] += x;
        __syncthreads();
    }
    int excl = s[t] - v + blockSums[blockIdx.x];
    if (i < N_NODES) {
        row_ptr[i] = excl;
        fillpos[i] = excl;
        if (i == N_NODES - 1) row_ptr[N_NODES] = excl + v;
    }
}

__global__ void fill_kernel(const int* __restrict__ adj_row,
                            const int* __restrict__ adj_col,
                            const float* __restrict__ adj_val,
                            int* __restrict__ fillpos,
                            int2* __restrict__ pedge) {
    int i = blockIdx.x * blockDim.x + threadIdx.x;
    int stride = gridDim.x * blockDim.x;
    for (; i < NNZ; i += stride) {
        int r = adj_row[i];
        int pos = atomicAdd(&fillpos[r], 1);
        pedge[pos] = make_int2(adj_col[i], __float_as_int(adj_val[i]));
    }
}

// ---------------------------------------------------------------------------
// SpMM: side[r][d] = sum over edges of row r: ego[col][d] * val
// one wave per row, lane = feature d. Coalesced int2 edge loads, readlane
// broadcast (SGPR col -> saddr gathers), 8 gathers in flight.
// ---------------------------------------------------------------------------
__global__ __launch_bounds__(256) void spmm_kernel(const int* __restrict__ row_ptr,
                                                   const int2* __restrict__ pedge,
                                                   const float* __restrict__ ego,
                                                   float* __restrict__ side) {
    int wave = (blockIdx.x * blockDim.x + threadIdx.x) >> 6;
    int lane = threadIdx.x & 63;
    if (wave >= N_NODES) return;
    int beg = row_ptr[wave];
    int end = row_ptr[wave + 1];
    float acc = 0.f;

    for (int base = beg; base < end; base += 64) {
        int cnt = min(64, end - base);
        int2 e = make_int2(0, 0);
        if (base + lane < end) e = pedge[base + lane];
        int cl = e.x;
        int vl = e.y;
        int j = 0;
        for (; j + 8 <= cnt; j += 8) {
            int c0 = __builtin_amdgcn_readlane(cl, j + 0);
            int c1 = __builtin_amdgcn_readlane(cl, j + 1);
            int c2 = __builtin_amdgcn_readlane(cl, j + 2);
            int c3 = __builtin_amdgcn_readlane(cl, j + 3);
            int c4 = __builtin_amdgcn_readlane(cl, j + 4);
            int c5 = __builtin_amdgcn_readlane(cl, j + 5);
            int c6 = __builtin_amdgcn_readlane(cl, j + 6);
            int c7 = __builtin_amdgcn_readlane(cl, j + 7);
            float g0 = ego[(c0 << 6) + lane];
            float g1 = ego[(c1 << 6) + lane];
            float g2 = ego[(c2 << 6) + lane];
            float g3 = ego[(c3 << 6) + lane];
            float g4 = ego[(c4 << 6) + lane];
            float g5 = ego[(c5 << 6) + lane];
            float g6 = ego[(c6 << 6) + lane];
            float g7 = ego[(c7 << 6) + lane];
            float v0 = __int_as_float(__builtin_amdgcn_readlane(vl, j + 0));
            float v1 = __int_as_float(__builtin_amdgcn_readlane(vl, j + 1));
            float v2 = __int_as_float(__builtin_amdgcn_readlane(vl, j + 2));
            float v3 = __int_as_float(__builtin_amdgcn_readlane(vl, j + 3));
            float v4 = __int_as_float(__builtin_amdgcn_readlane(vl, j + 4));
            float v5 = __int_as_float(__builtin_amdgcn_readlane(vl, j + 5));
            float v6 = __int_as_float(__builtin_amdgcn_readlane(vl, j + 6));
            float v7 = __int_as_float(__builtin_amdgcn_readlane(vl, j + 7));
            acc = fmaf(g0, v0, acc);
            acc = fmaf(g1, v1, acc);
            acc = fmaf(g2, v2, acc);
            acc = fmaf(g3, v3, acc);
            acc = fmaf(g4, v4, acc);
            acc = fmaf(g5, v5, acc);
            acc = fmaf(g6, v6, acc);
            acc = fmaf(g7, v7, acc);
        }
        for (; j < cnt; j++) {
            int   c = __builtin_amdgcn_readlane(cl, j);
            float v = __int_as_float(__builtin_amdgcn_readlane(vl, j));
            acc = fmaf(ego[(c << 6) + lane], v, acc);
        }
    }
    side[(size_t)wave * D + lane] = acc;
}

// ---------------------------------------------------------------------------
// dense: sum_e = lrelu(side@Wgc+bgc); bi_e = lrelu((ego*side)@Wbi+bbi)
//        ego_out = sum_e + bi_e ; out slot = l2norm(ego_out)
// 2 rows per wave; W staged in LDS; s/p rows staged in LDS, read as
// uniform float4 broadcasts; each W-column ds_read shared by both rows.
// ---------------------------------------------------------------------------
__global__ __launch_bounds__(256) void dense_kernel(const float* __restrict__ side,
                                                    const float* __restrict__ ego_in,
                                                    const float* __restrict__ Wgc,
                                                    const float* __restrict__ bgc,
                                                    const float* __restrict__ Wbi,
                                                    const float* __restrict__ bbi,
                                                    float* __restrict__ ego_out,
                                                    float* __restrict__ out,
                                                    int slot) {
    __shared__ float sWgc[D * D];
    __shared__ float sWbi[D * D];
    __shared__ float sbgc[D];
    __shared__ float sbbi[D];
    __shared__ float sRow[4][4][D];   // [waveInBlock][{s0,p0,s1,p1}][lane]

    for (int i = threadIdx.x; i < D * D; i += blockDim.x) {
        sWgc[i] = Wgc[i];
        sWbi[i] = Wbi[i];
    }
    if (threadIdx.x < D) {
        sbgc[threadIdx.x] = bgc[threadIdx.x];
        sbbi[threadIdx.x] = bbi[threadIdx.x];
    }
    __syncthreads();

    int lane = threadIdx.x & 63;
    int wib  = threadIdx.x >> 6;
    int wave = blockIdx.x * 4 + wib;
    int r0 = wave * 2;
    int r1 = r0 + 1;                  // N_NODES even; grid sized exactly

    float s0 = side[(size_t)r0 * D + lane];
    float e0 = ego_in[(size_t)r0 * D + lane];
    float s1 = side[(size_t)r1 * D + lane];
    float e1 = ego_in[(size_t)r1 * D + lane];
    float p0 = e0 * s0;
    float p1 = e1 * s1;

    sRow[wib][0][lane] = s0;
    sRow[wib][1][lane] = p0;
    sRow[wib][2][lane] = s1;
    sRow[wib][3][lane] = p1;

    float a10 = sbgc[lane];   // row0 gc
    float a20 = sbbi[lane];   // row0 bi
    float a11 = sbgc[lane];   // row1 gc
    float a21 = sbbi[lane];   // row1 bi

#pragma unroll
    for (int j4 = 0; j4 < D; j4 += 4) {
        float4 sv0 = *(const float4*)&sRow[wib][0][j4];
        float4 pv0 = *(const float4*)&sRow[wib][1][j4];
        float4 sv1 = *(const float4*)&sRow[wib][2][j4];
        float4 pv1 = *(const float4*)&sRow[wib][3][j4];
        const float* sA = (const float*)&sv0;
        const float* pA = (const float*)&pv0;
        const float* sB = (const float*)&sv1;
        const float* pB = (const float*)&pv1;
#pragma unroll
        for (int jj = 0; jj < 4; jj++) {
            float wg = sWgc[(j4 + jj) * D + lane];
            float wb = sWbi[(j4 + jj) * D + lane];
            a10 = fmaf(sA[jj], wg, a10);
            a20 = fmaf(pA[jj], wb, a20);
            a11 = fmaf(sB[jj], wg, a11);
            a21 = fmaf(pB[jj], wb, a21);
        }
    }

    a10 = a10 > 0.f ? a10 : 0.2f * a10;
    a20 = a20 > 0.f ? a20 : 0.2f * a20;
    a11 = a11 > 0.f ? a11 : 0.2f * a11;
    a21 = a21 > 0.f ? a21 : 0.2f * a21;
    float en0 = a10 + a20;
    float en1 = a11 + a21;

    float ss0 = en0 * en0;
    float ss1 = en1 * en1;
#pragma unroll
    for (int off = 32; off > 0; off >>= 1) {
        ss0 += __shfl_xor(ss0, off);
        ss1 += __shfl_xor(ss1, off);
    }
    float nrm0 = fmaxf(sqrtf(ss0), 1e-12f);
    float nrm1 = fmaxf(sqrtf(ss1), 1e-12f);

    ego_out[(size_t)r0 * D + lane] = en0;
    ego_out[(size_t)r1 * D + lane] = en1;
    out[(size_t)r0 * OUT_STRIDE + slot * D + lane] = en0 / nrm0;
    out[(size_t)r1 * OUT_STRIDE + slot * D + lane] = en1 / nrm1;
}

// ---------------------------------------------------------------------------
extern "C" void kernel_launch(void* const* d_in, const int* in_sizes, int n_in,
                              void* d_out, int out_size, void* d_ws, size_t ws_size,
                              hipStream_t stream) {
    const float* user_emb = (const float*)d_in[0];
    const float* item_emb = (const float*)d_in[1];
    const int*   adj_row  = (const int*)d_in[2];
    const int*   adj_col  = (const int*)d_in[3];
    const float* adj_val  = (const float*)d_in[4];
    const float* W_gc     = (const float*)d_in[5];
    const float* b_gc     = (const float*)d_in[6];
    const float* W_bi     = (const float*)d_in[7];
    const float* b_bi     = (const float*)d_in[8];
    float* out = (float*)d_out;

    char* ws = (char*)d_ws;
    size_t off = 0;
    auto alloc = [&](size_t bytes) -> void* {
        void* p = ws + off;
        off += (bytes + 255) / 256 * 256;
        return p;
    };
    float* ego0    = (float*)alloc((size_t)N_NODES * D * 4);
    float* ego1    = (float*)alloc((size_t)N_NODES * D * 4);
    float* side    = (float*)alloc((size_t)N_NODES * D * 4);
    int*   row_ptr = (int*)alloc((size_t)(N_NODES + 1) * 4);
    int*   counts  = (int*)alloc((size_t)N_NODES * 4);
    int*   fillpos = (int*)alloc((size_t)N_NODES * 4);
    int*   blockSums = (int*)alloc((size_t)N_SCAN_BLOCKS * 4);
    int2*  pedge   = (int2*)alloc((size_t)NNZ * 8);

    hipMemsetAsync(counts, 0, (size_t)N_NODES * 4, stream);

    hist_kernel<<<2048, 256, 0, stream>>>(adj_row, counts);
    scan_phase1<<<N_SCAN_BLOCKS, SCAN_BLOCK, 0, stream>>>(counts, blockSums);
    scan_phase2<<<1, 128, 0, stream>>>(blockSums);
    scan_phase3<<<N_SCAN_BLOCKS, SCAN_BLOCK, 0, stream>>>(counts, blockSums,
                                                          row_ptr, fillpos);
    fill_kernel<<<2048, 256, 0, stream>>>(adj_row, adj_col, adj_val,
                                          fillpos, pedge);

    init_ego_kernel<<<(N_NODES * (D / 4) + 255) / 256, 256, 0, stream>>>(
        user_emb, item_emb, ego0, out);

    float* bufs[2] = {ego0, ego1};
    for (int k = 0; k < N_LAYERS; k++) {
        spmm_kernel<<<(N_NODES + 3) / 4, 256, 0, stream>>>(
            row_ptr, pedge, bufs[k & 1], side);
        dense_kernel<<<N_NODES / 8, 256, 0, stream>>>(
            side, bufs[k & 1],
            W_gc + (size_t)k * D * D, b_gc + (size_t)k * D,
            W_bi + (size_t)k * D * D, b_bi + (size_t)k * D,
            bufs[(k + 1) & 1], out, k + 1);
    }
}

// Round 5
// 599.291 us; speedup vs baseline: 2.3080x; 1.2067x over previous
//
#include <hip/hip_runtime.h>

#define N_USERS 30000
#define N_ITEMS 60000
#define N_NODES 90000
#define NNZ     2000000
#define D       64
#define N_LAYERS 3
#define OUT_STRIDE ((N_LAYERS + 1) * D)   // 256

#define SCAN_BLOCK 1024
#define N_SCAN_BLOCKS ((N_NODES + SCAN_BLOCK - 1) / SCAN_BLOCK)   // 88

// ---------------------------------------------------------------------------
// init: ego = concat(user_emb, item_emb); out slot 0 = raw ego
// ---------------------------------------------------------------------------
__global__ void init_ego_kernel(const float* __restrict__ user_emb,
                                const float* __restrict__ item_emb,
                                float* __restrict__ ego,
                                float* __restrict__ out) {
    int idx = blockIdx.x * blockDim.x + threadIdx.x;   // over N_NODES*D/4 float4s
    const int total = N_NODES * (D / 4);
    if (idx >= total) return;
    int n  = idx / (D / 4);
    int c4 = idx % (D / 4);
    float4 v;
    if (n < N_USERS)
        v = ((const float4*)user_emb)[n * (D / 4) + c4];
    else
        v = ((const float4*)item_emb)[(n - N_USERS) * (D / 4) + c4];
    ((float4*)ego)[idx] = v;
    ((float4*)out)[n * (OUT_STRIDE / 4) + c4] = v;     // slot 0, raw ego
}

// ---------------------------------------------------------------------------
// CSR build: histogram(+rank) -> 3-phase scan -> atomic-free fill
// ---------------------------------------------------------------------------
__global__ void hist_kernel(const int* __restrict__ adj_row,
                            int* __restrict__ counts,
                            int* __restrict__ rank) {
    int i = blockIdx.x * blockDim.x + threadIdx.x;
    int stride = gridDim.x * blockDim.x;
    for (; i < NNZ; i += stride)
        rank[i] = atomicAdd(&counts[adj_row[i]], 1);   // rank within row
}

// phase 1: per-block sums (coalesced + LDS tree reduce)
__global__ __launch_bounds__(SCAN_BLOCK) void scan_phase1(
        const int* __restrict__ counts, int* __restrict__ blockSums) {
    __shared__ int red[SCAN_BLOCK];
    int i = blockIdx.x * SCAN_BLOCK + threadIdx.x;
    int v = (i < N_NODES) ? counts[i] : 0;
    red[threadIdx.x] = v;
    __syncthreads();
    for (int off = SCAN_BLOCK / 2; off > 0; off >>= 1) {
        if (threadIdx.x < off) red[threadIdx.x] += red[threadIdx.x + off];
        __syncthreads();
    }
    if (threadIdx.x == 0) blockSums[blockIdx.x] = red[0];
}

// phase 2: exclusive scan of the 88 block sums (single small block)
__global__ __launch_bounds__(128) void scan_phase2(int* __restrict__ blockSums) {
    __shared__ int s[128];
    int t = threadIdx.x;
    int v = (t < N_SCAN_BLOCKS) ? blockSums[t] : 0;
    s[t] = v;
    __syncthreads();
    for (int off = 1; off < 128; off <<= 1) {
        int x = (t >= off) ? s[t - off] : 0;
        __syncthreads();
        s[t] += x;
        __syncthreads();
    }
    if (t < N_SCAN_BLOCKS) blockSums[t] = s[t] - v;    // exclusive
}

// phase 3: local inclusive scan + block offset -> row_ptr
__global__ __launch_bounds__(SCAN_BLOCK) void scan_phase3(
        const int* __restrict__ counts, const int* __restrict__ blockSums,
        int* __restrict__ row_ptr) {
    __shared__ int s[SCAN_BLOCK];
    int t = threadIdx.x;
    int i = blockIdx.x * SCAN_BLOCK + t;
    int v = (i < N_NODES) ? counts[i] : 0;
    s[t] = v;
    __syncthreads();
    for (int off = 1; off < SCAN_BLOCK; off <<= 1) {
        int x = (t >= off) ? s[t - off] : 0;
        __syncthreads();
        s[t] += x;
        __syncthreads();
    }
    int excl = s[t] - v + blockSums[blockIdx.x];
    if (i < N_NODES) {
        row_ptr[i] = excl;
        if (i == N_NODES - 1) row_ptr[N_NODES] = excl + v;
    }
}

// atomic-free fill: pos = row_ptr[r] + rank[i]; scattered int2 write pipelines
__global__ void fill_kernel(const int* __restrict__ adj_row,
                            const int* __restrict__ adj_col,
                            const float* __restrict__ adj_val,
                            const int* __restrict__ rank,
                            const int* __restrict__ row_ptr,
                            int2* __restrict__ pedge) {
    int i = blockIdx.x * blockDim.x + threadIdx.x;
    int stride = gridDim.x * blockDim.x;
    for (; i < NNZ; i += stride) {
        int r = adj_row[i];
        int pos = row_ptr[r] + rank[i];
        pedge[pos] = make_int2(adj_col[i], __float_as_int(adj_val[i]));
    }
}

// ---------------------------------------------------------------------------
// SpMM: side[r][d] = sum over edges of row r: ego[col][d] * val
// one wave per row, lane = feature d. Coalesced int2 edge loads, readlane
// broadcast (SGPR col -> saddr gathers), 8 gathers in flight.
// ---------------------------------------------------------------------------
__global__ __launch_bounds__(256) void spmm_kernel(const int* __restrict__ row_ptr,
                                                   const int2* __restrict__ pedge,
                                                   const float* __restrict__ ego,
                                                   float* __restrict__ side) {
    int wave = (blockIdx.x * blockDim.x + threadIdx.x) >> 6;
    int lane = threadIdx.x & 63;
    if (wave >= N_NODES) return;
    int beg = row_ptr[wave];
    int end = row_ptr[wave + 1];
    float acc = 0.f;

    for (int base = beg; base < end; base += 64) {
        int cnt = min(64, end - base);
        int2 e = make_int2(0, 0);
        if (base + lane < end) e = pedge[base + lane];
        int cl = e.x;
        int vl = e.y;
        int j = 0;
        for (; j + 8 <= cnt; j += 8) {
            int c0 = __builtin_amdgcn_readlane(cl, j + 0);
            int c1 = __builtin_amdgcn_readlane(cl, j + 1);
            int c2 = __builtin_amdgcn_readlane(cl, j + 2);
            int c3 = __builtin_amdgcn_readlane(cl, j + 3);
            int c4 = __builtin_amdgcn_readlane(cl, j + 4);
            int c5 = __builtin_amdgcn_readlane(cl, j + 5);
            int c6 = __builtin_amdgcn_readlane(cl, j + 6);
            int c7 = __builtin_amdgcn_readlane(cl, j + 7);
            float g0 = ego[(c0 << 6) + lane];
            float g1 = ego[(c1 << 6) + lane];
            float g2 = ego[(c2 << 6) + lane];
            float g3 = ego[(c3 << 6) + lane];
            float g4 = ego[(c4 << 6) + lane];
            float g5 = ego[(c5 << 6) + lane];
            float g6 = ego[(c6 << 6) + lane];
            float g7 = ego[(c7 << 6) + lane];
            float v0 = __int_as_float(__builtin_amdgcn_readlane(vl, j + 0));
            float v1 = __int_as_float(__builtin_amdgcn_readlane(vl, j + 1));
            float v2 = __int_as_float(__builtin_amdgcn_readlane(vl, j + 2));
            float v3 = __int_as_float(__builtin_amdgcn_readlane(vl, j + 3));
            float v4 = __int_as_float(__builtin_amdgcn_readlane(vl, j + 4));
            float v5 = __int_as_float(__builtin_amdgcn_readlane(vl, j + 5));
            float v6 = __int_as_float(__builtin_amdgcn_readlane(vl, j + 6));
            float v7 = __int_as_float(__builtin_amdgcn_readlane(vl, j + 7));
            acc = fmaf(g0, v0, acc);
            acc = fmaf(g1, v1, acc);
            acc = fmaf(g2, v2, acc);
            acc = fmaf(g3, v3, acc);
            acc = fmaf(g4, v4, acc);
            acc = fmaf(g5, v5, acc);
            acc = fmaf(g6, v6, acc);
            acc = fmaf(g7, v7, acc);
        }
        for (; j < cnt; j++) {
            int   c = __builtin_amdgcn_readlane(cl, j);
            float v = __int_as_float(__builtin_amdgcn_readlane(vl, j));
            acc = fmaf(ego[(c << 6) + lane], v, acc);
        }
    }
    side[(size_t)wave * D + lane] = acc;
}

// ---------------------------------------------------------------------------
// dense: sum_e = lrelu(side@Wgc+bgc); bi_e = lrelu((ego*side)@Wbi+bbi)
//        ego_out = sum_e + bi_e ; out slot = l2norm(ego_out)
// 2 rows per wave; W staged in LDS; s/p rows staged in LDS, read as
// uniform float4 broadcasts; each W-column ds_read shared by both rows.
// ---------------------------------------------------------------------------
__global__ __launch_bounds__(256) void dense_kernel(const float* __restrict__ side,
                                                    const float* __restrict__ ego_in,
                                                    const float* __restrict__ Wgc,
                                                    const float* __restrict__ bgc,
                                                    const float* __restrict__ Wbi,
                                                    const float* __restrict__ bbi,
                                                    float* __restrict__ ego_out,
                                                    float* __restrict__ out,
                                                    int slot) {
    __shared__ float sWgc[D * D];
    __shared__ float sWbi[D * D];
    __shared__ float sbgc[D];
    __shared__ float sbbi[D];
    __shared__ float sRow[4][4][D];   // [waveInBlock][{s0,p0,s1,p1}][lane]

    for (int i = threadIdx.x; i < D * D; i += blockDim.x) {
        sWgc[i] = Wgc[i];
        sWbi[i] = Wbi[i];
    }
    if (threadIdx.x < D) {
        sbgc[threadIdx.x] = bgc[threadIdx.x];
        sbbi[threadIdx.x] = bbi[threadIdx.x];
    }
    __syncthreads();

    int lane = threadIdx.x & 63;
    int wib  = threadIdx.x >> 6;
    int wave = blockIdx.x * 4 + wib;
    int r0 = wave * 2;
    int r1 = r0 + 1;                  // N_NODES even; grid sized exactly

    float s0 = side[(size_t)r0 * D + lane];
    float e0 = ego_in[(size_t)r0 * D + lane];
    float s1 = side[(size_t)r1 * D + lane];
    float e1 = ego_in[(size_t)r1 * D + lane];
    float p0 = e0 * s0;
    float p1 = e1 * s1;

    sRow[wib][0][lane] = s0;
    sRow[wib][1][lane] = p0;
    sRow[wib][2][lane] = s1;
    sRow[wib][3][lane] = p1;

    float a10 = sbgc[lane];   // row0 gc
    float a20 = sbbi[lane];   // row0 bi
    float a11 = sbgc[lane];   // row1 gc
    float a21 = sbbi[lane];   // row1 bi

#pragma unroll
    for (int j4 = 0; j4 < D; j4 += 4) {
        float4 sv0 = *(const float4*)&sRow[wib][0][j4];
        float4 pv0 = *(const float4*)&sRow[wib][1][j4];
        float4 sv1 = *(const float4*)&sRow[wib][2][j4];
        float4 pv1 = *(const float4*)&sRow[wib][3][j4];
        const float* sA = (const float*)&sv0;
        const float* pA = (const float*)&pv0;
        const float* sB = (const float*)&sv1;
        const float* pB = (const float*)&pv1;
#pragma unroll
        for (int jj = 0; jj < 4; jj++) {
            float wg = sWgc[(j4 + jj) * D + lane];
            float wb = sWbi[(j4 + jj) * D + lane];
            a10 = fmaf(sA[jj], wg, a10);
            a20 = fmaf(pA[jj], wb, a20);
            a11 = fmaf(sB[jj], wg, a11);
            a21 = fmaf(pB[jj], wb, a21);
        }
    }

    a10 = a10 > 0.f ? a10 : 0.2f * a10;
    a20 = a20 > 0.f ? a20 : 0.2f * a20;
    a11 = a11 > 0.f ? a11 : 0.2f * a11;
    a21 = a21 > 0.f ? a21 : 0.2f * a21;
    float en0 = a10 + a20;
    float en1 = a11 + a21;

    float ss0 = en0 * en0;
    float ss1 = en1 * en1;
#pragma unroll
    for (int off = 32; off > 0; off >>= 1) {
        ss0 += __shfl_xor(ss0, off);
        ss1 += __shfl_xor(ss1, off);
    }
    float nrm0 = fmaxf(sqrtf(ss0), 1e-12f);
    float nrm1 = fmaxf(sqrtf(ss1), 1e-12f);

    ego_out[(size_t)r0 * D + lane] = en0;
    ego_out[(size_t)r1 * D + lane] = en1;
    out[(size_t)r0 * OUT_STRIDE + slot * D + lane] = en0 / nrm0;
    out[(size_t)r1 * OUT_STRIDE + slot * D + lane] = en1 / nrm1;
}

// ---------------------------------------------------------------------------
extern "C" void kernel_launch(void* const* d_in, const int* in_sizes, int n_in,
                              void* d_out, int out_size, void* d_ws, size_t ws_size,
                              hipStream_t stream) {
    const float* user_emb = (const float*)d_in[0];
    const float* item_emb = (const float*)d_in[1];
    const int*   adj_row  = (const int*)d_in[2];
    const int*   adj_col  = (const int*)d_in[3];
    const float* adj_val  = (const float*)d_in[4];
    const float* W_gc     = (const float*)d_in[5];
    const float* b_gc     = (const float*)d_in[6];
    const float* W_bi     = (const float*)d_in[7];
    const float* b_bi     = (const float*)d_in[8];
    float* out = (float*)d_out;

    char* ws = (char*)d_ws;
    size_t off = 0;
    auto alloc = [&](size_t bytes) -> void* {
        void* p = ws + off;
        off += (bytes + 255) / 256 * 256;
        return p;
    };
    float* ego0    = (float*)alloc((size_t)N_NODES * D * 4);
    float* ego1    = (float*)alloc((size_t)N_NODES * D * 4);
    float* side    = (float*)alloc((size_t)N_NODES * D * 4);
    int*   row_ptr = (int*)alloc((size_t)(N_NODES + 1) * 4);
    int*   counts  = (int*)alloc((size_t)N_NODES * 4);
    int*   rank    = (int*)alloc((size_t)NNZ * 4);
    int*   blockSums = (int*)alloc((size_t)N_SCAN_BLOCKS * 4);
    int2*  pedge   = (int2*)alloc((size_t)NNZ * 8);

    hipMemsetAsync(counts, 0, (size_t)N_NODES * 4, stream);

    hist_kernel<<<2048, 256, 0, stream>>>(adj_row, counts, rank);
    scan_phase1<<<N_SCAN_BLOCKS, SCAN_BLOCK, 0, stream>>>(counts, blockSums);
    scan_phase2<<<1, 128, 0, stream>>>(blockSums);
    scan_phase3<<<N_SCAN_BLOCKS, SCAN_BLOCK, 0, stream>>>(counts, blockSums,
                                                          row_ptr);
    fill_kernel<<<2048, 256, 0, stream>>>(adj_row, adj_col, adj_val,
                                          rank, row_ptr, pedge);

    init_ego_kernel<<<(N_NODES * (D / 4) + 255) / 256, 256, 0, stream>>>(
        user_emb, item_emb, ego0, out);

    float* bufs[2] = {ego0, ego1};
    for (int k = 0; k < N_LAYERS; k++) {
        spmm_kernel<<<(N_NODES + 3) / 4, 256, 0, stream>>>(
            row_ptr, pedge, bufs[k & 1], side);
        dense_kernel<<<N_NODES / 8, 256, 0, stream>>>(
            side, bufs[k & 1],
            W_gc + (size_t)k * D * D, b_gc + (size_t)k * D,
            W_bi + (size_t)k * D * D, b_bi + (size_t)k * D,
            bufs[(k + 1) & 1], out, k + 1);
    }
}

// Round 6
// 411.156 us; speedup vs baseline: 3.3640x; 1.4576x over previous
//
#include <hip/hip_runtime.h>

#define N_USERS 30000
#define N_ITEMS 60000
#define N_NODES 90000
#define NNZ     2000000
#define D       64
#define N_LAYERS 3
#define OUT_STRIDE ((N_LAYERS + 1) * D)   // 256

#define SCAN_BLOCK 1024
#define N_SCAN_BLOCKS ((N_NODES + SCAN_BLOCK - 1) / SCAN_BLOCK)   // 88

#define N_CHUNKS (N_NODES / 16)           // 5625 16-row chunks

typedef __attribute__((ext_vector_type(8))) short bf16x8;   // 8 bf16 = 4 VGPR
typedef __attribute__((ext_vector_type(4))) float f32x4;

// truncating f32 -> bf16 (keeps residual exactly representable)
__device__ __forceinline__ short bf16hi(float x) {
    return (short)(__float_as_uint(x) >> 16);
}
__device__ __forceinline__ float bf16hif(float x) {
    return __uint_as_float(__float_as_uint(x) & 0xffff0000u);
}

// ---------------------------------------------------------------------------
// init: ego = concat(user_emb, item_emb); out slot 0 = raw ego
// ---------------------------------------------------------------------------
__global__ void init_ego_kernel(const float* __restrict__ user_emb,
                                const float* __restrict__ item_emb,
                                float* __restrict__ ego,
                                float* __restrict__ out) {
    int idx = blockIdx.x * blockDim.x + threadIdx.x;   // over N_NODES*D/4 float4s
    const int total = N_NODES * (D / 4);
    if (idx >= total) return;
    int n  = idx / (D / 4);
    int c4 = idx % (D / 4);
    float4 v;
    if (n < N_USERS)
        v = ((const float4*)user_emb)[n * (D / 4) + c4];
    else
        v = ((const float4*)item_emb)[(n - N_USERS) * (D / 4) + c4];
    ((float4*)ego)[idx] = v;
    ((float4*)out)[n * (OUT_STRIDE / 4) + c4] = v;     // slot 0, raw ego
}

// ---------------------------------------------------------------------------
// CSR build: histogram(+rank) -> 3-phase scan -> atomic-free fill
// ---------------------------------------------------------------------------
__global__ void hist_kernel(const int* __restrict__ adj_row,
                            int* __restrict__ counts,
                            int* __restrict__ rank) {
    int i = blockIdx.x * blockDim.x + threadIdx.x;
    int stride = gridDim.x * blockDim.x;
    for (; i < NNZ; i += stride)
        rank[i] = atomicAdd(&counts[adj_row[i]], 1);   // rank within row
}

__global__ __launch_bounds__(SCAN_BLOCK) void scan_phase1(
        const int* __restrict__ counts, int* __restrict__ blockSums) {
    __shared__ int red[SCAN_BLOCK];
    int i = blockIdx.x * SCAN_BLOCK + threadIdx.x;
    int v = (i < N_NODES) ? counts[i] : 0;
    red[threadIdx.x] = v;
    __syncthreads();
    for (int off = SCAN_BLOCK / 2; off > 0; off >>= 1) {
        if (threadIdx.x < off) red[threadIdx.x] += red[threadIdx.x + off];
        __syncthreads();
    }
    if (threadIdx.x == 0) blockSums[blockIdx.x] = red[0];
}

__global__ __launch_bounds__(128) void scan_phase2(int* __restrict__ blockSums) {
    __shared__ int s[128];
    int t = threadIdx.x;
    int v = (t < N_SCAN_BLOCKS) ? blockSums[t] : 0;
    s[t] = v;
    __syncthreads();
    for (int off = 1; off < 128; off <<= 1) {
        int x = (t >= off) ? s[t - off] : 0;
        __syncthreads();
        s[t] += x;
        __syncthreads();
    }
    if (t < N_SCAN_BLOCKS) blockSums[t] = s[t] - v;    // exclusive
}

__global__ __launch_bounds__(SCAN_BLOCK) void scan_phase3(
        const int* __restrict__ counts, const int* __restrict__ blockSums,
        int* __restrict__ row_ptr) {
    __shared__ int s[SCAN_BLOCK];
    int t = threadIdx.x;
    int i = blockIdx.x * SCAN_BLOCK + t;
    int v = (i < N_NODES) ? counts[i] : 0;
    s[t] = v;
    __syncthreads();
    for (int off = 1; off < SCAN_BLOCK; off <<= 1) {
        int x = (t >= off) ? s[t - off] : 0;
        __syncthreads();
        s[t] += x;
        __syncthreads();
    }
    int excl = s[t] - v + blockSums[blockIdx.x];
    if (i < N_NODES) {
        row_ptr[i] = excl;
        if (i == N_NODES - 1) row_ptr[N_NODES] = excl + v;
    }
}

// atomic-free fill: pos = row_ptr[r] + rank[i]
__global__ void fill_kernel(const int* __restrict__ adj_row,
                            const int* __restrict__ adj_col,
                            const float* __restrict__ adj_val,
                            const int* __restrict__ rank,
                            const int* __restrict__ row_ptr,
                            int2* __restrict__ pedge) {
    int i = blockIdx.x * blockDim.x + threadIdx.x;
    int stride = gridDim.x * blockDim.x;
    for (; i < NNZ; i += stride) {
        int r = adj_row[i];
        int pos = row_ptr[r] + rank[i];
        pedge[pos] = make_int2(adj_col[i], __float_as_int(adj_val[i]));
    }
}

// ---------------------------------------------------------------------------
// SpMM: side[r][d] = sum over edges of row r: ego[col][d] * val
// ---------------------------------------------------------------------------
__global__ __launch_bounds__(256) void spmm_kernel(const int* __restrict__ row_ptr,
                                                   const int2* __restrict__ pedge,
                                                   const float* __restrict__ ego,
                                                   float* __restrict__ side) {
    int wave = (blockIdx.x * blockDim.x + threadIdx.x) >> 6;
    int lane = threadIdx.x & 63;
    if (wave >= N_NODES) return;
    int beg = row_ptr[wave];
    int end = row_ptr[wave + 1];
    float acc = 0.f;

    for (int base = beg; base < end; base += 64) {
        int cnt = min(64, end - base);
        int2 e = make_int2(0, 0);
        if (base + lane < end) e = pedge[base + lane];
        int cl = e.x;
        int vl = e.y;
        int j = 0;
        for (; j + 8 <= cnt; j += 8) {
            int c0 = __builtin_amdgcn_readlane(cl, j + 0);
            int c1 = __builtin_amdgcn_readlane(cl, j + 1);
            int c2 = __builtin_amdgcn_readlane(cl, j + 2);
            int c3 = __builtin_amdgcn_readlane(cl, j + 3);
            int c4 = __builtin_amdgcn_readlane(cl, j + 4);
            int c5 = __builtin_amdgcn_readlane(cl, j + 5);
            int c6 = __builtin_amdgcn_readlane(cl, j + 6);
            int c7 = __builtin_amdgcn_readlane(cl, j + 7);
            float g0 = ego[(c0 << 6) + lane];
            float g1 = ego[(c1 << 6) + lane];
            float g2 = ego[(c2 << 6) + lane];
            float g3 = ego[(c3 << 6) + lane];
            float g4 = ego[(c4 << 6) + lane];
            float g5 = ego[(c5 << 6) + lane];
            float g6 = ego[(c6 << 6) + lane];
            float g7 = ego[(c7 << 6) + lane];
            float v0 = __int_as_float(__builtin_amdgcn_readlane(vl, j + 0));
            float v1 = __int_as_float(__builtin_amdgcn_readlane(vl, j + 1));
            float v2 = __int_as_float(__builtin_amdgcn_readlane(vl, j + 2));
            float v3 = __int_as_float(__builtin_amdgcn_readlane(vl, j + 3));
            float v4 = __int_as_float(__builtin_amdgcn_readlane(vl, j + 4));
            float v5 = __int_as_float(__builtin_amdgcn_readlane(vl, j + 5));
            float v6 = __int_as_float(__builtin_amdgcn_readlane(vl, j + 6));
            float v7 = __int_as_float(__builtin_amdgcn_readlane(vl, j + 7));
            acc = fmaf(g0, v0, acc);
            acc = fmaf(g1, v1, acc);
            acc = fmaf(g2, v2, acc);
            acc = fmaf(g3, v3, acc);
            acc = fmaf(g4, v4, acc);
            acc = fmaf(g5, v5, acc);
            acc = fmaf(g6, v6, acc);
            acc = fmaf(g7, v7, acc);
        }
        for (; j < cnt; j++) {
            int   c = __builtin_amdgcn_readlane(cl, j);
            float v = __int_as_float(__builtin_amdgcn_readlane(vl, j));
            acc = fmaf(ego[(c << 6) + lane], v, acc);
        }
    }
    side[(size_t)wave * D + lane] = acc;
}

// ---------------------------------------------------------------------------
// dense via MFMA (hi/lo bf16 split, 3-term):
//   sum_e = lrelu(side@Wgc+bgc); bi_e = lrelu((ego*side)@Wbi+bbi)
//   ego_out = sum_e + bi_e ; out slot = l2norm(ego_out)
// One wave per 16-row chunk-iteration. W pre-split/packed in LDS.
// k-map (bijective, used for BOTH A and B -> result independent of HW k-order):
//   frag elem j, lane group g=lane>>4:  k = q*32 + g*8 + j
// C/D layout (HW-verified m89): col = lane&15, row = (lane>>4)*4 + reg
// ---------------------------------------------------------------------------
__global__ __launch_bounds__(512) void dense_mfma_kernel(
        const float* __restrict__ side,
        const float* __restrict__ ego_in,
        const float* __restrict__ Wgc,
        const float* __restrict__ bgc,
        const float* __restrict__ Wbi,
        const float* __restrict__ bbi,
        float* __restrict__ ego_out,
        float* __restrict__ out,
        int slot) {
    // [mat][hilo][ntile][kstep][lane] : 2*2*4*2*64 frags * 16B = 32 KB
    __shared__ bf16x8 packB[2][2][4][2][64];

    int tid  = threadIdx.x;
    int lane = tid & 63;
    int wib  = tid >> 6;                 // 8 waves/block
    int g    = lane >> 4;                // 0..3
    int li   = lane & 15;                // 0..15

    // ---- pack W fragments (once per block); W read direct from global (L2-hot)
    for (int it = wib; it < 16; it += 8) {
        int mat = it >> 3;               // 0..1
        int t   = (it >> 1) & 3;         // 0..3
        int q   = it & 1;                // 0..1
        const float* W = mat ? Wbi : Wgc;
        bf16x8 fh, fl;
#pragma unroll
        for (int j = 0; j < 8; j++) {
            int k = q * 32 + g * 8 + j;
            float w = W[k * D + t * 16 + li];
            float whf = bf16hif(w);
            fh[j] = bf16hi(w);
            fl[j] = bf16hi(w - whf);
        }
        packB[mat][0][t][q][lane] = fh;
        packB[mat][1][t][q][lane] = fl;
    }
    __syncthreads();

    float biasgc[4], biasbi[4];
#pragma unroll
    for (int t = 0; t < 4; t++) {
        biasgc[t] = bgc[t * 16 + li];
        biasbi[t] = bbi[t * 16 + li];
    }

    int wid = blockIdx.x * 8 + wib;
    int nw  = gridDim.x * 8;

    for (int c = wid; c < N_CHUNKS; c += nw) {
        int rbase = c * 16;
        const float* srow = side   + (size_t)(rbase + li) * D;
        const float* erow = ego_in + (size_t)(rbase + li) * D;

        // lane loads cols [g*8, g*8+8) and [32+g*8, 32+g*8+8) of its row
        f32x4 s0 = *(const f32x4*)(srow + g * 8);
        f32x4 s1 = *(const f32x4*)(srow + g * 8 + 4);
        f32x4 s2 = *(const f32x4*)(srow + 32 + g * 8);
        f32x4 s3 = *(const f32x4*)(srow + 32 + g * 8 + 4);
        f32x4 e0 = *(const f32x4*)(erow + g * 8);
        f32x4 e1 = *(const f32x4*)(erow + g * 8 + 4);
        f32x4 e2 = *(const f32x4*)(erow + 32 + g * 8);
        f32x4 e3 = *(const f32x4*)(erow + 32 + g * 8 + 4);

        bf16x8 sh[2], sl[2], ph[2], pl[2];
#pragma unroll
        for (int j = 0; j < 4; j++) {
            float sa = s0[j], sb = s1[j], sc = s2[j], sd = s3[j];
            float pa = e0[j] * sa, pb = e1[j] * sb, pc = e2[j] * sc, pd = e3[j] * sd;
            sh[0][j]     = bf16hi(sa); sl[0][j]     = bf16hi(sa - bf16hif(sa));
            sh[0][4 + j] = bf16hi(sb); sl[0][4 + j] = bf16hi(sb - bf16hif(sb));
            sh[1][j]     = bf16hi(sc); sl[1][j]     = bf16hi(sc - bf16hif(sc));
            sh[1][4 + j] = bf16hi(sd); sl[1][4 + j] = bf16hi(sd - bf16hif(sd));
            ph[0][j]     = bf16hi(pa); pl[0][j]     = bf16hi(pa - bf16hif(pa));
            ph[0][4 + j] = bf16hi(pb); pl[0][4 + j] = bf16hi(pb - bf16hif(pb));
            ph[1][j]     = bf16hi(pc); pl[1][j]     = bf16hi(pc - bf16hif(pc));
            ph[1][4 + j] = bf16hi(pd); pl[1][4 + j] = bf16hi(pd - bf16hif(pd));
        }

        f32x4 accgc[4], accbi[4];
#pragma unroll
        for (int t = 0; t < 4; t++) {
            accgc[t] = (f32x4){biasgc[t], biasgc[t], biasgc[t], biasgc[t]};
            accbi[t] = (f32x4){biasbi[t], biasbi[t], biasbi[t], biasbi[t]};
        }

#pragma unroll
        for (int t = 0; t < 4; t++) {
#pragma unroll
            for (int q = 0; q < 2; q++) {
                bf16x8 bh = packB[0][0][t][q][lane];
                bf16x8 bl = packB[0][1][t][q][lane];
                accgc[t] = __builtin_amdgcn_mfma_f32_16x16x32_bf16(sh[q], bh, accgc[t], 0, 0, 0);
                accgc[t] = __builtin_amdgcn_mfma_f32_16x16x32_bf16(sl[q], bh, accgc[t], 0, 0, 0);
                accgc[t] = __builtin_amdgcn_mfma_f32_16x16x32_bf16(sh[q], bl, accgc[t], 0, 0, 0);
                bf16x8 ch = packB[1][0][t][q][lane];
                bf16x8 cl2 = packB[1][1][t][q][lane];
                accbi[t] = __builtin_amdgcn_mfma_f32_16x16x32_bf16(ph[q], ch, accbi[t], 0, 0, 0);
                accbi[t] = __builtin_amdgcn_mfma_f32_16x16x32_bf16(pl[q], ch, accbi[t], 0, 0, 0);
                accbi[t] = __builtin_amdgcn_mfma_f32_16x16x32_bf16(ph[q], cl2, accbi[t], 0, 0, 0);
            }
        }

        // epilogue: lrelu + sum, l2 norm per row (row = rbase + g*4 + reg)
        float en[4][4];
        float ss[4] = {0.f, 0.f, 0.f, 0.f};
#pragma unroll
        for (int t = 0; t < 4; t++) {
#pragma unroll
            for (int r = 0; r < 4; r++) {
                float a1 = accgc[t][r]; a1 = a1 > 0.f ? a1 : 0.2f * a1;
                float a2 = accbi[t][r]; a2 = a2 > 0.f ? a2 : 0.2f * a2;
                float e = a1 + a2;
                en[t][r] = e;
                ss[r] += e * e;
            }
        }
#pragma unroll
        for (int r = 0; r < 4; r++) {
            float s = ss[r];
            s += __shfl_xor(s, 8);
            s += __shfl_xor(s, 4);
            s += __shfl_xor(s, 2);
            s += __shfl_xor(s, 1);
            float inv = 1.0f / fmaxf(sqrtf(s), 1e-12f);
            int row = rbase + g * 4 + r;
#pragma unroll
            for (int t = 0; t < 4; t++) {
                ego_out[(size_t)row * D + t * 16 + li] = en[t][r];
                out[(size_t)row * OUT_STRIDE + slot * D + t * 16 + li] = en[t][r] * inv;
            }
        }
    }
}

// ---------------------------------------------------------------------------
extern "C" void kernel_launch(void* const* d_in, const int* in_sizes, int n_in,
                              void* d_out, int out_size, void* d_ws, size_t ws_size,
                              hipStream_t stream) {
    const float* user_emb = (const float*)d_in[0];
    const float* item_emb = (const float*)d_in[1];
    const int*   adj_row  = (const int*)d_in[2];
    const int*   adj_col  = (const int*)d_in[3];
    const float* adj_val  = (const float*)d_in[4];
    const float* W_gc     = (const float*)d_in[5];
    const float* b_gc     = (const float*)d_in[6];
    const float* W_bi     = (const float*)d_in[7];
    const float* b_bi     = (const float*)d_in[8];
    float* out = (float*)d_out;

    char* ws = (char*)d_ws;
    size_t off = 0;
    auto alloc = [&](size_t bytes) -> void* {
        void* p = ws + off;
        off += (bytes + 255) / 256 * 256;
        return p;
    };
    float* ego0    = (float*)alloc((size_t)N_NODES * D * 4);
    float* ego1    = (float*)alloc((size_t)N_NODES * D * 4);
    float* side    = (float*)alloc((size_t)N_NODES * D * 4);
    int*   row_ptr = (int*)alloc((size_t)(N_NODES + 1) * 4);
    int*   counts  = (int*)alloc((size_t)N_NODES * 4);
    int*   rank    = (int*)alloc((size_t)NNZ * 4);
    int*   blockSums = (int*)alloc((size_t)N_SCAN_BLOCKS * 4);
    int2*  pedge   = (int2*)alloc((size_t)NNZ * 8);

    hipMemsetAsync(counts, 0, (size_t)N_NODES * 4, stream);

    hist_kernel<<<2048, 256, 0, stream>>>(adj_row, counts, rank);
    scan_phase1<<<N_SCAN_BLOCKS, SCAN_BLOCK, 0, stream>>>(counts, blockSums);
    scan_phase2<<<1, 128, 0, stream>>>(blockSums);
    scan_phase3<<<N_SCAN_BLOCKS, SCAN_BLOCK, 0, stream>>>(counts, blockSums,
                                                          row_ptr);
    fill_kernel<<<2048, 256, 0, stream>>>(adj_row, adj_col, adj_val,
                                          rank, row_ptr, pedge);

    init_ego_kernel<<<(N_NODES * (D / 4) + 255) / 256, 256, 0, stream>>>(
        user_emb, item_emb, ego0, out);

    float* bufs[2] = {ego0, ego1};
    for (int k = 0; k < N_LAYERS; k++) {
        spmm_kernel<<<(N_NODES + 3) / 4, 256, 0, stream>>>(
            row_ptr, pedge, bufs[k & 1], side);
        dense_mfma_kernel<<<352, 512, 0, stream>>>(
            side, bufs[k & 1],
            W_gc + (size_t)k * D * D, b_gc + (size_t)k * D,
            W_bi + (size_t)k * D * D, b_bi + (size_t)k * D,
            bufs[(k + 1) & 1], out, k + 1);
    }
}

// Round 7
// 367.323 us; speedup vs baseline: 3.7655x; 1.1193x over previous
//
#include <hip/hip_runtime.h>
#include <hip/hip_fp16.h>

#define N_USERS 30000
#define N_ITEMS 60000
#define N_NODES 90000
#define NNZ     2000000
#define D       64
#define N_LAYERS 3
#define OUT_STRIDE ((N_LAYERS + 1) * D)   // 256

#define SCAN_BLOCK 1024
#define N_SCAN_BLOCKS ((N_NODES + SCAN_BLOCK - 1) / SCAN_BLOCK)   // 88

#define N_CHUNKS (N_NODES / 16)           // 5625 16-row chunks

typedef __attribute__((ext_vector_type(8))) short bf16x8;   // 8 bf16 = 4 VGPR
typedef __attribute__((ext_vector_type(4))) float f32x4;

// truncating f32 -> bf16 (keeps residual exactly representable)
__device__ __forceinline__ short bf16hi(float x) {
    return (short)(__float_as_uint(x) >> 16);
}
__device__ __forceinline__ float bf16hif(float x) {
    return __uint_as_float(__float_as_uint(x) & 0xffff0000u);
}

// ---------------------------------------------------------------------------
// init: ego = concat(user_emb, item_emb); egoh = f16 copy; out slot 0 = ego
// ---------------------------------------------------------------------------
__global__ void init_ego_kernel(const float* __restrict__ user_emb,
                                const float* __restrict__ item_emb,
                                float* __restrict__ ego,
                                __half* __restrict__ egoh,
                                float* __restrict__ out) {
    int idx = blockIdx.x * blockDim.x + threadIdx.x;   // over N_NODES*D/4 float4s
    const int total = N_NODES * (D / 4);
    if (idx >= total) return;
    int n  = idx / (D / 4);
    int c4 = idx % (D / 4);
    float4 v;
    if (n < N_USERS)
        v = ((const float4*)user_emb)[n * (D / 4) + c4];
    else
        v = ((const float4*)item_emb)[(n - N_USERS) * (D / 4) + c4];
    ((float4*)ego)[idx] = v;
    ((float4*)out)[n * (OUT_STRIDE / 4) + c4] = v;     // slot 0, raw ego
    __half2* hp = (__half2*)egoh;
    hp[idx * 2 + 0] = __floats2half2_rn(v.x, v.y);
    hp[idx * 2 + 1] = __floats2half2_rn(v.z, v.w);
}

// ---------------------------------------------------------------------------
// CSR build: batched histogram(+rank) -> 3-phase scan -> atomic-free fill
// ---------------------------------------------------------------------------
// 4 edges/thread: int4 load, 4 atomics in flight, int4 rank store
__global__ void hist_kernel(const int4* __restrict__ adj_row4,
                            int* __restrict__ counts,
                            int4* __restrict__ rank4) {
    int i = blockIdx.x * blockDim.x + threadIdx.x;
    if (i >= NNZ / 4) return;
    int4 r = adj_row4[i];
    int4 k;
    k.x = atomicAdd(&counts[r.x], 1);
    k.y = atomicAdd(&counts[r.y], 1);
    k.z = atomicAdd(&counts[r.z], 1);
    k.w = atomicAdd(&counts[r.w], 1);
    rank4[i] = k;
}

__global__ __launch_bounds__(SCAN_BLOCK) void scan_phase1(
        const int* __restrict__ counts, int* __restrict__ blockSums) {
    __shared__ int red[SCAN_BLOCK];
    int i = blockIdx.x * SCAN_BLOCK + threadIdx.x;
    int v = (i < N_NODES) ? counts[i] : 0;
    red[threadIdx.x] = v;
    __syncthreads();
    for (int off = SCAN_BLOCK / 2; off > 0; off >>= 1) {
        if (threadIdx.x < off) red[threadIdx.x] += red[threadIdx.x + off];
        __syncthreads();
    }
    if (threadIdx.x == 0) blockSums[blockIdx.x] = red[0];
}

__global__ __launch_bounds__(128) void scan_phase2(int* __restrict__ blockSums) {
    __shared__ int s[128];
    int t = threadIdx.x;
    int v = (t < N_SCAN_BLOCKS) ? blockSums[t] : 0;
    s[t] = v;
    __syncthreads();
    for (int off = 1; off < 128; off <<= 1) {
        int x = (t >= off) ? s[t - off] : 0;
        __syncthreads();
        s[t] += x;
        __syncthreads();
    }
    if (t < N_SCAN_BLOCKS) blockSums[t] = s[t] - v;    // exclusive
}

__global__ __launch_bounds__(SCAN_BLOCK) void scan_phase3(
        const int* __restrict__ counts, const int* __restrict__ blockSums,
        int* __restrict__ row_ptr) {
    __shared__ int s[SCAN_BLOCK];
    int t = threadIdx.x;
    int i = blockIdx.x * SCAN_BLOCK + t;
    int v = (i < N_NODES) ? counts[i] : 0;
    s[t] = v;
    __syncthreads();
    for (int off = 1; off < SCAN_BLOCK; off <<= 1) {
        int x = (t >= off) ? s[t - off] : 0;
        __syncthreads();
        s[t] += x;
        __syncthreads();
    }
    int excl = s[t] - v + blockSums[blockIdx.x];
    if (i < N_NODES) {
        row_ptr[i] = excl;
        if (i == N_NODES - 1) row_ptr[N_NODES] = excl + v;
    }
}

// atomic-free fill: pos = row_ptr[r] + rank[i]
__global__ void fill_kernel(const int* __restrict__ adj_row,
                            const int* __restrict__ adj_col,
                            const float* __restrict__ adj_val,
                            const int* __restrict__ rank,
                            const int* __restrict__ row_ptr,
                            int2* __restrict__ pedge) {
    int i = blockIdx.x * blockDim.x + threadIdx.x;
    int stride = gridDim.x * blockDim.x;
    for (; i < NNZ; i += stride) {
        int r = adj_row[i];
        int pos = row_ptr[r] + rank[i];
        pedge[pos] = make_int2(adj_col[i], __float_as_int(adj_val[i]));
    }
}

// ---------------------------------------------------------------------------
// SpMM: side[r][d] = sum over edges of row r: egoh[col][d] * val  (f16 gather)
// one wave per row, lane = feature d. Coalesced int2 edge loads, readlane
// broadcast (SGPR col -> saddr gathers), 8 gathers in flight, 128B/edge.
// ---------------------------------------------------------------------------
__global__ __launch_bounds__(256) void spmm_kernel(const int* __restrict__ row_ptr,
                                                   const int2* __restrict__ pedge,
                                                   const __half* __restrict__ egoh,
                                                   float* __restrict__ side) {
    int wave = (blockIdx.x * blockDim.x + threadIdx.x) >> 6;
    int lane = threadIdx.x & 63;
    if (wave >= N_NODES) return;
    int beg = row_ptr[wave];
    int end = row_ptr[wave + 1];
    float acc = 0.f;

    for (int base = beg; base < end; base += 64) {
        int cnt = min(64, end - base);
        int2 e = make_int2(0, 0);
        if (base + lane < end) e = pedge[base + lane];
        int cl = e.x;
        int vl = e.y;
        int j = 0;
        for (; j + 8 <= cnt; j += 8) {
            int c0 = __builtin_amdgcn_readlane(cl, j + 0);
            int c1 = __builtin_amdgcn_readlane(cl, j + 1);
            int c2 = __builtin_amdgcn_readlane(cl, j + 2);
            int c3 = __builtin_amdgcn_readlane(cl, j + 3);
            int c4 = __builtin_amdgcn_readlane(cl, j + 4);
            int c5 = __builtin_amdgcn_readlane(cl, j + 5);
            int c6 = __builtin_amdgcn_readlane(cl, j + 6);
            int c7 = __builtin_amdgcn_readlane(cl, j + 7);
            float g0 = __half2float(egoh[(c0 << 6) + lane]);
            float g1 = __half2float(egoh[(c1 << 6) + lane]);
            float g2 = __half2float(egoh[(c2 << 6) + lane]);
            float g3 = __half2float(egoh[(c3 << 6) + lane]);
            float g4 = __half2float(egoh[(c4 << 6) + lane]);
            float g5 = __half2float(egoh[(c5 << 6) + lane]);
            float g6 = __half2float(egoh[(c6 << 6) + lane]);
            float g7 = __half2float(egoh[(c7 << 6) + lane]);
            float v0 = __int_as_float(__builtin_amdgcn_readlane(vl, j + 0));
            float v1 = __int_as_float(__builtin_amdgcn_readlane(vl, j + 1));
            float v2 = __int_as_float(__builtin_amdgcn_readlane(vl, j + 2));
            float v3 = __int_as_float(__builtin_amdgcn_readlane(vl, j + 3));
            float v4 = __int_as_float(__builtin_amdgcn_readlane(vl, j + 4));
            float v5 = __int_as_float(__builtin_amdgcn_readlane(vl, j + 5));
            float v6 = __int_as_float(__builtin_amdgcn_readlane(vl, j + 6));
            float v7 = __int_as_float(__builtin_amdgcn_readlane(vl, j + 7));
            acc = fmaf(g0, v0, acc);
            acc = fmaf(g1, v1, acc);
            acc = fmaf(g2, v2, acc);
            acc = fmaf(g3, v3, acc);
            acc = fmaf(g4, v4, acc);
            acc = fmaf(g5, v5, acc);
            acc = fmaf(g6, v6, acc);
            acc = fmaf(g7, v7, acc);
        }
        for (; j < cnt; j++) {
            int   c = __builtin_amdgcn_readlane(cl, j);
            float v = __int_as_float(__builtin_amdgcn_readlane(vl, j));
            acc = fmaf(__half2float(egoh[(c << 6) + lane]), v, acc);
        }
    }
    side[(size_t)wave * D + lane] = acc;
}

// ---------------------------------------------------------------------------
// dense via MFMA (hi/lo bf16 split, 3-term). Also emits f16 ego for next spmm.
// k-map bijective & identical for A/B; C/D layout HW-verified (m89).
// ---------------------------------------------------------------------------
__global__ __launch_bounds__(512) void dense_mfma_kernel(
        const float* __restrict__ side,
        const float* __restrict__ ego_in,
        const float* __restrict__ Wgc,
        const float* __restrict__ bgc,
        const float* __restrict__ Wbi,
        const float* __restrict__ bbi,
        float* __restrict__ ego_out,
        __half* __restrict__ egoh_out,
        float* __restrict__ out,
        int slot) {
    // [mat][hilo][ntile][kstep][lane] : 2*2*4*2*64 frags * 16B = 32 KB
    __shared__ bf16x8 packB[2][2][4][2][64];

    int tid  = threadIdx.x;
    int lane = tid & 63;
    int wib  = tid >> 6;                 // 8 waves/block
    int g    = lane >> 4;                // 0..3
    int li   = lane & 15;                // 0..15

    for (int it = wib; it < 16; it += 8) {
        int mat = it >> 3;               // 0..1
        int t   = (it >> 1) & 3;         // 0..3
        int q   = it & 1;                // 0..1
        const float* W = mat ? Wbi : Wgc;
        bf16x8 fh, fl;
#pragma unroll
        for (int j = 0; j < 8; j++) {
            int k = q * 32 + g * 8 + j;
            float w = W[k * D + t * 16 + li];
            float whf = bf16hif(w);
            fh[j] = bf16hi(w);
            fl[j] = bf16hi(w - whf);
        }
        packB[mat][0][t][q][lane] = fh;
        packB[mat][1][t][q][lane] = fl;
    }
    __syncthreads();

    float biasgc[4], biasbi[4];
#pragma unroll
    for (int t = 0; t < 4; t++) {
        biasgc[t] = bgc[t * 16 + li];
        biasbi[t] = bbi[t * 16 + li];
    }

    int wid = blockIdx.x * 8 + wib;
    int nw  = gridDim.x * 8;

    for (int c = wid; c < N_CHUNKS; c += nw) {
        int rbase = c * 16;
        const float* srow = side   + (size_t)(rbase + li) * D;
        const float* erow = ego_in + (size_t)(rbase + li) * D;

        f32x4 s0 = *(const f32x4*)(srow + g * 8);
        f32x4 s1 = *(const f32x4*)(srow + g * 8 + 4);
        f32x4 s2 = *(const f32x4*)(srow + 32 + g * 8);
        f32x4 s3 = *(const f32x4*)(srow + 32 + g * 8 + 4);
        f32x4 e0 = *(const f32x4*)(erow + g * 8);
        f32x4 e1 = *(const f32x4*)(erow + g * 8 + 4);
        f32x4 e2 = *(const f32x4*)(erow + 32 + g * 8);
        f32x4 e3 = *(const f32x4*)(erow + 32 + g * 8 + 4);

        bf16x8 sh[2], sl[2], ph[2], pl[2];
#pragma unroll
        for (int j = 0; j < 4; j++) {
            float sa = s0[j], sb = s1[j], sc = s2[j], sd = s3[j];
            float pa = e0[j] * sa, pb = e1[j] * sb, pc = e2[j] * sc, pd = e3[j] * sd;
            sh[0][j]     = bf16hi(sa); sl[0][j]     = bf16hi(sa - bf16hif(sa));
            sh[0][4 + j] = bf16hi(sb); sl[0][4 + j] = bf16hi(sb - bf16hif(sb));
            sh[1][j]     = bf16hi(sc); sl[1][j]     = bf16hi(sc - bf16hif(sc));
            sh[1][4 + j] = bf16hi(sd); sl[1][4 + j] = bf16hi(sd - bf16hif(sd));
            ph[0][j]     = bf16hi(pa); pl[0][j]     = bf16hi(pa - bf16hif(pa));
            ph[0][4 + j] = bf16hi(pb); pl[0][4 + j] = bf16hi(pb - bf16hif(pb));
            ph[1][j]     = bf16hi(pc); pl[1][j]     = bf16hi(pc - bf16hif(pc));
            ph[1][4 + j] = bf16hi(pd); pl[1][4 + j] = bf16hi(pd - bf16hif(pd));
        }

        f32x4 accgc[4], accbi[4];
#pragma unroll
        for (int t = 0; t < 4; t++) {
            accgc[t] = (f32x4){biasgc[t], biasgc[t], biasgc[t], biasgc[t]};
            accbi[t] = (f32x4){biasbi[t], biasbi[t], biasbi[t], biasbi[t]};
        }

#pragma unroll
        for (int t = 0; t < 4; t++) {
#pragma unroll
            for (int q = 0; q < 2; q++) {
                bf16x8 bh = packB[0][0][t][q][lane];
                bf16x8 bl = packB[0][1][t][q][lane];
                accgc[t] = __builtin_amdgcn_mfma_f32_16x16x32_bf16(sh[q], bh, accgc[t], 0, 0, 0);
                accgc[t] = __builtin_amdgcn_mfma_f32_16x16x32_bf16(sl[q], bh, accgc[t], 0, 0, 0);
                accgc[t] = __builtin_amdgcn_mfma_f32_16x16x32_bf16(sh[q], bl, accgc[t], 0, 0, 0);
                bf16x8 ch = packB[1][0][t][q][lane];
                bf16x8 cl2 = packB[1][1][t][q][lane];
                accbi[t] = __builtin_amdgcn_mfma_f32_16x16x32_bf16(ph[q], ch, accbi[t], 0, 0, 0);
                accbi[t] = __builtin_amdgcn_mfma_f32_16x16x32_bf16(pl[q], ch, accbi[t], 0, 0, 0);
                accbi[t] = __builtin_amdgcn_mfma_f32_16x16x32_bf16(ph[q], cl2, accbi[t], 0, 0, 0);
            }
        }

        float en[4][4];
        float ss[4] = {0.f, 0.f, 0.f, 0.f};
#pragma unroll
        for (int t = 0; t < 4; t++) {
#pragma unroll
            for (int r = 0; r < 4; r++) {
                float a1 = accgc[t][r]; a1 = a1 > 0.f ? a1 : 0.2f * a1;
                float a2 = accbi[t][r]; a2 = a2 > 0.f ? a2 : 0.2f * a2;
                float e = a1 + a2;
                en[t][r] = e;
                ss[r] += e * e;
            }
        }
#pragma unroll
        for (int r = 0; r < 4; r++) {
            float s = ss[r];
            s += __shfl_xor(s, 8);
            s += __shfl_xor(s, 4);
            s += __shfl_xor(s, 2);
            s += __shfl_xor(s, 1);
            float inv = 1.0f / fmaxf(sqrtf(s), 1e-12f);
            int row = rbase + g * 4 + r;
#pragma unroll
            for (int t = 0; t < 4; t++) {
                ego_out[(size_t)row * D + t * 16 + li] = en[t][r];
                egoh_out[(size_t)row * D + t * 16 + li] = __float2half(en[t][r]);
                out[(size_t)row * OUT_STRIDE + slot * D + t * 16 + li] = en[t][r] * inv;
            }
        }
    }
}

// ---------------------------------------------------------------------------
extern "C" void kernel_launch(void* const* d_in, const int* in_sizes, int n_in,
                              void* d_out, int out_size, void* d_ws, size_t ws_size,
                              hipStream_t stream) {
    const float* user_emb = (const float*)d_in[0];
    const float* item_emb = (const float*)d_in[1];
    const int*   adj_row  = (const int*)d_in[2];
    const int*   adj_col  = (const int*)d_in[3];
    const float* adj_val  = (const float*)d_in[4];
    const float* W_gc     = (const float*)d_in[5];
    const float* b_gc     = (const float*)d_in[6];
    const float* W_bi     = (const float*)d_in[7];
    const float* b_bi     = (const float*)d_in[8];
    float* out = (float*)d_out;

    char* ws = (char*)d_ws;
    size_t off = 0;
    auto alloc = [&](size_t bytes) -> void* {
        void* p = ws + off;
        off += (bytes + 255) / 256 * 256;
        return p;
    };
    float*  ego0    = (float*)alloc((size_t)N_NODES * D * 4);
    float*  ego1    = (float*)alloc((size_t)N_NODES * D * 4);
    __half* egoh0   = (__half*)alloc((size_t)N_NODES * D * 2);
    __half* egoh1   = (__half*)alloc((size_t)N_NODES * D * 2);
    float*  side    = (float*)alloc((size_t)N_NODES * D * 4);
    int*    row_ptr = (int*)alloc((size_t)(N_NODES + 1) * 4);
    int*    counts  = (int*)alloc((size_t)N_NODES * 4);
    int*    rank    = (int*)alloc((size_t)NNZ * 4);
    int*    blockSums = (int*)alloc((size_t)N_SCAN_BLOCKS * 4);
    int2*   pedge   = (int2*)alloc((size_t)NNZ * 8);

    hipMemsetAsync(counts, 0, (size_t)N_NODES * 4, stream);

    hist_kernel<<<(NNZ / 4 + 255) / 256, 256, 0, stream>>>(
        (const int4*)adj_row, counts, (int4*)rank);
    scan_phase1<<<N_SCAN_BLOCKS, SCAN_BLOCK, 0, stream>>>(counts, blockSums);
    scan_phase2<<<1, 128, 0, stream>>>(blockSums);
    scan_phase3<<<N_SCAN_BLOCKS, SCAN_BLOCK, 0, stream>>>(counts, blockSums,
                                                          row_ptr);
    fill_kernel<<<2048, 256, 0, stream>>>(adj_row, adj_col, adj_val,
                                          rank, row_ptr, pedge);

    init_ego_kernel<<<(N_NODES * (D / 4) + 255) / 256, 256, 0, stream>>>(
        user_emb, item_emb, ego0, egoh0, out);

    float*  bufs[2]  = {ego0, ego1};
    __half* bufsh[2] = {egoh0, egoh1};
    for (int k = 0; k < N_LAYERS; k++) {
        spmm_kernel<<<(N_NODES + 3) / 4, 256, 0, stream>>>(
            row_ptr, pedge, bufsh[k & 1], side);
        dense_mfma_kernel<<<352, 512, 0, stream>>>(
            side, bufs[k & 1],
            W_gc + (size_t)k * D * D, b_gc + (size_t)k * D,
            W_bi + (size_t)k * D * D, b_bi + (size_t)k * D,
            bufs[(k + 1) & 1], bufsh[(k + 1) & 1], out, k + 1);
    }
}